// Round 1
// baseline (6741.773 us; speedup 1.0000x reference)
//
#include <hip/hip_runtime.h>
#include <hip/hip_bf16.h>
#include <cstdint>
#include <cstddef>

// ---- model dims ----
constexpr int LNUM = 12;
constexpr int BB   = 2;
constexpr int SS   = 1024;
constexpr int CC   = 768;
constexpr int HH   = 12;
constexpr int DD   = 64;      // C/H
constexpr int FFD  = 3072;    // 4C
constexpr int VV   = 50257;
constexpr int VPAD = 50304;   // V rounded up to 128
constexpr int MM   = BB * SS; // 2048 token rows

typedef unsigned short u16;
typedef short     s16x8 __attribute__((ext_vector_type(8)));
typedef float     f32x4 __attribute__((ext_vector_type(4)));
typedef u16       u16x4 __attribute__((ext_vector_type(4)));
typedef u16       u16x8 __attribute__((ext_vector_type(8)));

__device__ __forceinline__ float bf2f(u16 v) {
    return __uint_as_float(((unsigned)v) << 16);
}
__device__ __forceinline__ u16 f2bf(float f) {
    unsigned u = __float_as_uint(f);
    return (u16)((u + 0x7fffu + ((u >> 16) & 1u)) >> 16);
}

// ---------------- weight prep ----------------

// wte [V][C] f32 -> bf16 [VPAD][C], pad rows zero
__global__ __launch_bounds__(256) void wte_conv_kernel(const float* __restrict__ wte,
                                                       u16* __restrict__ out) {
    size_t i4 = ((size_t)blockIdx.x * 256 + threadIdx.x) * 4;
    if (i4 >= (size_t)VPAD * CC) return;
    size_t r = i4 / CC;
    u16x4 o;
    if (r < (size_t)VV) {
        const float4 v = *(const float4*)&wte[i4];
        o[0] = f2bf(v.x); o[1] = f2bf(v.y); o[2] = f2bf(v.z); o[3] = f2bf(v.w);
    } else {
        o[0] = o[1] = o[2] = o[3] = 0;
    }
    *(u16x4*)&out[i4] = o;
}

// in: [L][R][Cn] f32   out: [L][Cn][R] bf16   (R,Cn multiples of 32)
__global__ __launch_bounds__(256) void transpose_conv_kernel(const float* __restrict__ in,
                                                             u16* __restrict__ out,
                                                             int R, int Cn) {
    __shared__ float tile[32][33];
    const float* inp = in + (size_t)blockIdx.z * R * Cn;
    u16* outp = out + (size_t)blockIdx.z * R * Cn;
    int c  = blockIdx.x * 32 + threadIdx.x;
    int r0 = blockIdx.y * 32;
#pragma unroll
    for (int i = 0; i < 4; ++i) {
        int r = r0 + threadIdx.y + i * 8;
        tile[threadIdx.y + i * 8][threadIdx.x] = inp[(size_t)r * Cn + c];
    }
    __syncthreads();
    int oc = r0 + threadIdx.x; // output col = input row (k)
#pragma unroll
    for (int i = 0; i < 4; ++i) {
        int orow = blockIdx.x * 32 + threadIdx.y + i * 8; // output row (n)
        outp[(size_t)orow * R + oc] = f2bf(tile[threadIdx.x][threadIdx.y + i * 8]);
    }
}

// ---------------- embedding ----------------
__global__ __launch_bounds__(256) void embed_kernel(const int* __restrict__ idx,
                                                    const float* __restrict__ wte,
                                                    const float* __restrict__ wpe,
                                                    float* __restrict__ h) {
    int row = blockIdx.x;          // 0..2047
    int s   = row & (SS - 1);
    int tok = idx[row];
    const float* we = wte + (size_t)tok * CC;
    const float* pe = wpe + (size_t)s * CC;
    float* hr = h + (size_t)row * CC;
    for (int c = threadIdx.x; c < CC; c += 256) hr[c] = we[c] + pe[c];
}

// ---------------- layernorm: f32 in -> bf16 out ----------------
__global__ __launch_bounds__(256) void ln_kernel(const float* __restrict__ h,
                                                 const float* __restrict__ w,
                                                 const float* __restrict__ b,
                                                 u16* __restrict__ x) {
    int row = blockIdx.x, tid = threadIdx.x;
    const float* hr = h + (size_t)row * CC;
    float v0 = hr[tid], v1 = hr[tid + 256], v2 = hr[tid + 512];
    float s  = v0 + v1 + v2;
    float s2 = v0 * v0 + v1 * v1 + v2 * v2;
#pragma unroll
    for (int off = 32; off; off >>= 1) {
        s  += __shfl_xor(s, off);
        s2 += __shfl_xor(s2, off);
    }
    __shared__ float rs[4], rs2[4], stat[2];
    int wid = tid >> 6;
    if ((tid & 63) == 0) { rs[wid] = s; rs2[wid] = s2; }
    __syncthreads();
    if (tid == 0) {
        float ts  = rs[0] + rs[1] + rs[2] + rs[3];
        float ts2 = rs2[0] + rs2[1] + rs2[2] + rs2[3];
        float mean = ts * (1.0f / CC);
        float var  = ts2 * (1.0f / CC) - mean * mean;
        stat[0] = mean;
        stat[1] = rsqrtf(var + 1e-5f);
    }
    __syncthreads();
    float mean = stat[0], rstd = stat[1];
    size_t base = (size_t)row * CC;
    x[base + tid]       = f2bf((v0 - mean) * rstd * w[tid]       + b[tid]);
    x[base + tid + 256] = f2bf((v1 - mean) * rstd * w[tid + 256] + b[tid + 256]);
    x[base + tid + 512] = f2bf((v2 - mean) * rstd * w[tid + 512] + b[tid + 512]);
}

// ---------------- GEMM: C[M,N] = A[M,K] @ Bt[N,K]^T  (bf16 in, f32 acc) ----------------
// EPI: 0 = bias -> bf16 out        (qkv)
//      1 = bias+gelu -> bf16 out   (fc)
//      2 = bias, residual add into f32 outf (proj, fc2)
//      3 = no bias, f32 out with col<nmax guard (lm_head)
template <int BM, int BN, int EPI>
__global__ __launch_bounds__((BM / 64) * (BN / 64) * 64)
void gemm_bt_kernel(const u16* __restrict__ A, const u16* __restrict__ Bt,
                    const float* __restrict__ bias, float* __restrict__ outf,
                    u16* __restrict__ outb, int K, long long ldo, int nmax) {
    constexpr int NWM = BM / 64, NWN = BN / 64;
    constexpr int THREADS = NWM * NWN * 64;
    __shared__ u16 As[BM * 64];
    __shared__ u16 Bs[BN * 64];
    const int tid  = threadIdx.x;
    const int lane = tid & 63;
    const int wid  = tid >> 6;
    const int wm   = wid % NWM;
    const int wn   = wid / NWM;
    const int bm0  = blockIdx.y * BM;
    const int bn0  = blockIdx.x * BN;
    const int l15  = lane & 15;
    const int lq   = lane >> 4;

    f32x4 acc[4][4];
#pragma unroll
    for (int m = 0; m < 4; ++m)
#pragma unroll
        for (int n = 0; n < 4; ++n) acc[m][n] = (f32x4){0.f, 0.f, 0.f, 0.f};

    for (int kt = 0; kt < K; kt += 64) {
        // stage A tile [BM][64], B tile [BN][64] (reg-staged)
#pragma unroll
        for (int it = 0; it < BM * 64 / (THREADS * 8); ++it) {
            int e = (it * THREADS + tid) * 8;
            int r = e >> 6, c = e & 63;
            *(u16x8*)&As[e] = *(const u16x8*)&A[(size_t)(bm0 + r) * K + kt + c];
        }
#pragma unroll
        for (int it = 0; it < BN * 64 / (THREADS * 8); ++it) {
            int e = (it * THREADS + tid) * 8;
            int r = e >> 6, c = e & 63;
            *(u16x8*)&Bs[e] = *(const u16x8*)&Bt[(size_t)(bn0 + r) * K + kt + c];
        }
        __syncthreads();
#pragma unroll
        for (int ks = 0; ks < 2; ++ks) {
            s16x8 af[4], bfr[4];
#pragma unroll
            for (int m = 0; m < 4; ++m)
                af[m] = *(const s16x8*)&As[(wm * 64 + m * 16 + l15) * 64 + ks * 32 + lq * 8];
#pragma unroll
            for (int n = 0; n < 4; ++n)
                bfr[n] = *(const s16x8*)&Bs[(wn * 64 + n * 16 + l15) * 64 + ks * 32 + lq * 8];
#pragma unroll
            for (int m = 0; m < 4; ++m)
#pragma unroll
                for (int n = 0; n < 4; ++n)
                    acc[m][n] = __builtin_amdgcn_mfma_f32_16x16x32_bf16(af[m], bfr[n], acc[m][n], 0, 0, 0);
        }
        __syncthreads();
    }

    // epilogue: C/D layout col=lane&15, row=4*(lane>>4)+reg
#pragma unroll
    for (int m = 0; m < 4; ++m) {
#pragma unroll
        for (int n = 0; n < 4; ++n) {
#pragma unroll
            for (int r = 0; r < 4; ++r) {
                int row = bm0 + wm * 64 + m * 16 + lq * 4 + r;
                int col = bn0 + wn * 64 + n * 16 + l15;
                float v = acc[m][n][r];
                if (EPI != 3) v += bias[col];
                if (EPI == 1) {
                    float xg = v;
                    v = 0.5f * xg * (1.0f + tanhf(0.7978845608028654f * (xg + 0.044715f * xg * xg * xg)));
                }
                if (EPI == 0 || EPI == 1) {
                    outb[(size_t)row * ldo + col] = f2bf(v);
                } else if (EPI == 2) {
                    outf[(size_t)row * ldo + col] += v;
                } else {
                    if (col < nmax) outf[(size_t)row * ldo + col] = v;
                }
            }
        }
    }
}

// ---------------- attention (vector f32, bf16 in/out) ----------------
// grid: B*H*S/4 blocks, 4 waves/block, one query row per wave
__global__ __launch_bounds__(256) void attn_kernel(const u16* __restrict__ qkv,
                                                   u16* __restrict__ o) {
    __shared__ float ps[4][SS];
    const int tid = threadIdx.x, lane = tid & 63, wid = tid >> 6;
    const int gid = blockIdx.x;
    const int bh  = gid >> 8;               // (B*H) index; 256 row-groups each
    const int s   = ((gid & 255) << 2) + wid;
    const int b   = bh / HH, hh = bh % HH;

    const size_t qkv_row0 = (size_t)b * SS * (3 * CC);
    const u16* qrow = qkv + qkv_row0 + (size_t)s * (3 * CC) + hh * DD;

    float q[DD];
#pragma unroll
    for (int ch = 0; ch < 8; ++ch) {
        u16x8 t = *(const u16x8*)&qrow[ch * 8];
#pragma unroll
        for (int e = 0; e < 8; ++e) q[ch * 8 + e] = bf2f(t[e]);
    }

    const int nt = s + 1;
    const u16* kbase = qkv + qkv_row0 + CC + hh * DD;
    float sc[16];
#pragma unroll
    for (int j = 0; j < 16; ++j) {
        int t = j * 64 + lane;
        if (t < nt) {
            const u16* kr = kbase + (size_t)t * (3 * CC);
            float dot = 0.f;
#pragma unroll
            for (int ch = 0; ch < 8; ++ch) {
                u16x8 kv = *(const u16x8*)&kr[ch * 8];
#pragma unroll
                for (int e = 0; e < 8; ++e) dot += bf2f(kv[e]) * q[ch * 8 + e];
            }
            sc[j] = dot * 0.125f;
        } else {
            sc[j] = -3.0e38f;
        }
    }
    float m = sc[0];
#pragma unroll
    for (int j = 1; j < 16; ++j) m = fmaxf(m, sc[j]);
#pragma unroll
    for (int off = 32; off; off >>= 1) m = fmaxf(m, __shfl_xor(m, off));
    float l = 0.f;
#pragma unroll
    for (int j = 0; j < 16; ++j) {
        float p = exp2f((sc[j] - m) * 1.4426950408889634f);
        ps[wid][j * 64 + lane] = p;
        l += p;
    }
#pragma unroll
    for (int off = 32; off; off >>= 1) l += __shfl_xor(l, off);
    float inv = 1.f / l;
    asm volatile("s_waitcnt lgkmcnt(0)" ::: "memory");

    const u16* vbase = qkv + qkv_row0 + 2 * CC + hh * DD + lane;
    float od = 0.f;
#pragma unroll 4
    for (int t = 0; t < nt; ++t) od += ps[wid][t] * bf2f(vbase[(size_t)t * (3 * CC)]);
    o[((size_t)b * SS + s) * CC + hh * DD + lane] = f2bf(od * inv);
}

// ---------------- loss ----------------
__global__ __launch_bounds__(256) void lse_kernel(const float* __restrict__ logits,
                                                  const int* __restrict__ tgt,
                                                  float* __restrict__ lossp) {
    int row = blockIdx.x, tid = threadIdx.x;
    const float* lr = logits + (size_t)row * VV;
    float m = -3.0e38f, s = 0.f;
    for (int i = tid; i < VV; i += 256) {
        float x = lr[i];
        float nm = fmaxf(m, x);
        s = s * __expf(m - nm) + __expf(x - nm);
        m = nm;
    }
#pragma unroll
    for (int off = 32; off; off >>= 1) {
        float om = __shfl_xor(m, off), os = __shfl_xor(s, off);
        float nm = fmaxf(m, om);
        s = s * __expf(m - nm) + os * __expf(om - nm);
        m = nm;
    }
    __shared__ float rm[4], rsh[4];
    int wid = tid >> 6;
    if ((tid & 63) == 0) { rm[wid] = m; rsh[wid] = s; }
    __syncthreads();
    if (tid == 0) {
        float M = fmaxf(fmaxf(rm[0], rm[1]), fmaxf(rm[2], rm[3]));
        float S = rsh[0] * __expf(rm[0] - M) + rsh[1] * __expf(rm[1] - M) +
                  rsh[2] * __expf(rm[2] - M) + rsh[3] * __expf(rm[3] - M);
        float lse = M + __logf(S);
        lossp[row] = lse - lr[tgt[row]];
    }
}

__global__ __launch_bounds__(256) void loss_reduce_kernel(const float* __restrict__ lossp,
                                                          float* __restrict__ out) {
    int tid = threadIdx.x;
    float s = 0.f;
    for (int i = tid; i < MM; i += 256) s += lossp[i];
#pragma unroll
    for (int off = 32; off; off >>= 1) s += __shfl_xor(s, off);
    __shared__ float r[4];
    if ((tid & 63) == 0) r[tid >> 6] = s;
    __syncthreads();
    if (tid == 0) out[0] = (r[0] + r[1] + r[2] + r[3]) * (1.0f / MM);
}

// ---------------- host ----------------
extern "C" void kernel_launch(void* const* d_in, const int* in_sizes, int n_in,
                              void* d_out, int out_size, void* d_ws, size_t ws_size,
                              hipStream_t stream) {
    const int*   idx     = (const int*)  d_in[0];
    const int*   targets = (const int*)  d_in[1];
    const float* wte     = (const float*)d_in[2];
    const float* wpe     = (const float*)d_in[3];
    const float* ln1w    = (const float*)d_in[4];
    const float* ln1b    = (const float*)d_in[5];
    const float* qkvw    = (const float*)d_in[6];
    const float* qkvbi   = (const float*)d_in[7];
    const float* projw   = (const float*)d_in[8];
    const float* projbi  = (const float*)d_in[9];
    const float* ln2w    = (const float*)d_in[10];
    const float* ln2b    = (const float*)d_in[11];
    const float* fcw     = (const float*)d_in[12];
    const float* fcbi    = (const float*)d_in[13];
    const float* fc2w    = (const float*)d_in[14];
    const float* fc2bi   = (const float*)d_in[15];
    const float* lnfw    = (const float*)d_in[16];
    const float* lnfb    = (const float*)d_in[17];
    float* logits = (float*)d_out;

    char* wsb = (char*)d_ws;
    size_t off = 0;
    auto alloc = [&](size_t n) -> char* {
        char* p = wsb + off;
        off = (off + n + 255) & ~(size_t)255;
        return p;
    };
    u16*   wteT  = (u16*)  alloc((size_t)VPAD * CC * 2);
    u16*   qkvT  = (u16*)  alloc((size_t)LNUM * 3 * CC * CC * 2);
    u16*   projT = (u16*)  alloc((size_t)LNUM * CC * CC * 2);
    u16*   fcT   = (u16*)  alloc((size_t)LNUM * FFD * CC * 2);
    u16*   fc2T  = (u16*)  alloc((size_t)LNUM * CC * FFD * 2);
    float* h     = (float*)alloc((size_t)MM * CC * 4);
    u16*   xb    = (u16*)  alloc((size_t)MM * CC * 2);
    u16*   qkvb  = (u16*)  alloc((size_t)MM * 3 * CC * 2);
    u16*   ob    = (u16*)  alloc((size_t)MM * CC * 2);
    u16*   gb    = (u16*)  alloc((size_t)MM * FFD * 2);
    float* lossp = (float*)alloc((size_t)MM * 4);

    // weight prep
    {
        int blocks = (int)(((size_t)VPAD * CC / 4 + 255) / 256);
        wte_conv_kernel<<<blocks, 256, 0, stream>>>(wte, wteT);
    }
    transpose_conv_kernel<<<dim3(3 * CC / 32, CC / 32, LNUM), dim3(32, 8), 0, stream>>>(qkvw, qkvT, CC, 3 * CC);
    transpose_conv_kernel<<<dim3(CC / 32, CC / 32, LNUM),     dim3(32, 8), 0, stream>>>(projw, projT, CC, CC);
    transpose_conv_kernel<<<dim3(FFD / 32, CC / 32, LNUM),    dim3(32, 8), 0, stream>>>(fcw, fcT, CC, FFD);
    transpose_conv_kernel<<<dim3(CC / 32, FFD / 32, LNUM),    dim3(32, 8), 0, stream>>>(fc2w, fc2T, FFD, CC);

    embed_kernel<<<MM, 256, 0, stream>>>(idx, wte, wpe, h);

    for (int l = 0; l < LNUM; ++l) {
        const u16* qkvT_l  = qkvT  + (size_t)l * 3 * CC * CC;
        const u16* projT_l = projT + (size_t)l * CC * CC;
        const u16* fcT_l   = fcT   + (size_t)l * FFD * CC;
        const u16* fc2T_l  = fc2T  + (size_t)l * CC * FFD;

        ln_kernel<<<MM, 256, 0, stream>>>(h, ln1w + (size_t)l * CC, ln1b + (size_t)l * CC, xb);
        gemm_bt_kernel<128, 128, 0><<<dim3(3 * CC / 128, MM / 128), 256, 0, stream>>>(
            xb, qkvT_l, qkvbi + (size_t)l * 3 * CC, nullptr, qkvb, CC, 3 * CC, 0);
        attn_kernel<<<BB * HH * SS / 4, 256, 0, stream>>>(qkvb, ob);
        gemm_bt_kernel<64, 64, 2><<<dim3(CC / 64, MM / 64), 64, 0, stream>>>(
            ob, projT_l, projbi + (size_t)l * CC, h, nullptr, CC, CC, 0);
        ln_kernel<<<MM, 256, 0, stream>>>(h, ln2w + (size_t)l * CC, ln2b + (size_t)l * CC, xb);
        gemm_bt_kernel<128, 128, 1><<<dim3(FFD / 128, MM / 128), 256, 0, stream>>>(
            xb, fcT_l, fcbi + (size_t)l * FFD, nullptr, gb, CC, FFD, 0);
        gemm_bt_kernel<64, 64, 2><<<dim3(CC / 64, MM / 64), 64, 0, stream>>>(
            gb, fc2T_l, fc2bi + (size_t)l * CC, h, nullptr, FFD, CC, 0);
    }

    ln_kernel<<<MM, 256, 0, stream>>>(h, lnfw, lnfb, xb);
    gemm_bt_kernel<128, 128, 3><<<dim3(VPAD / 128, MM / 128), 256, 0, stream>>>(
        xb, wteT, nullptr, logits, nullptr, CC, VV, VV);

    lse_kernel<<<MM, 256, 0, stream>>>(logits, targets, lossp);
    loss_reduce_kernel<<<1, 256, 0, stream>>>(lossp, logits + (size_t)MM * VV);
}

// Round 2
// 3034.774 us; speedup vs baseline: 2.2215x; 2.2215x over previous
//
#include <hip/hip_runtime.h>
#include <hip/hip_bf16.h>
#include <cstdint>
#include <cstddef>

// ---- model dims ----
constexpr int LNUM = 12;
constexpr int BB   = 2;
constexpr int SS   = 1024;
constexpr int CC   = 768;
constexpr int HH   = 12;
constexpr int DD   = 64;      // C/H
constexpr int FFD  = 3072;    // 4C
constexpr int VV   = 50257;
constexpr int VPAD = 50304;   // V rounded up to 128
constexpr int MM   = BB * SS; // 2048 token rows

typedef unsigned short u16;
typedef short     s16x8 __attribute__((ext_vector_type(8)));
typedef float     f32x4 __attribute__((ext_vector_type(4)));
typedef u16       u16x4 __attribute__((ext_vector_type(4)));
typedef u16       u16x8 __attribute__((ext_vector_type(8)));

__device__ __forceinline__ float bf2f(u16 v) {
    return __uint_as_float(((unsigned)v) << 16);
}
__device__ __forceinline__ u16 f2bf(float f) {
    unsigned u = __float_as_uint(f);
    return (u16)((u + 0x7fffu + ((u >> 16) & 1u)) >> 16);
}

// ---------------- weight prep ----------------

// wte [V][C] f32 -> bf16 [VPAD][C], pad rows zero
__global__ __launch_bounds__(256) void wte_conv_kernel(const float* __restrict__ wte,
                                                       u16* __restrict__ out) {
    size_t i4 = ((size_t)blockIdx.x * 256 + threadIdx.x) * 4;
    if (i4 >= (size_t)VPAD * CC) return;
    size_t r = i4 / CC;
    u16x4 o;
    if (r < (size_t)VV) {
        const float4 v = *(const float4*)&wte[i4];
        o[0] = f2bf(v.x); o[1] = f2bf(v.y); o[2] = f2bf(v.z); o[3] = f2bf(v.w);
    } else {
        o[0] = o[1] = o[2] = o[3] = 0;
    }
    *(u16x4*)&out[i4] = o;
}

// in: [L][R][Cn] f32   out: [L][Cn][R] bf16   (R,Cn multiples of 32)
__global__ __launch_bounds__(256) void transpose_conv_kernel(const float* __restrict__ in,
                                                             u16* __restrict__ out,
                                                             int R, int Cn) {
    __shared__ float tile[32][33];
    const float* inp = in + (size_t)blockIdx.z * R * Cn;
    u16* outp = out + (size_t)blockIdx.z * R * Cn;
    int c  = blockIdx.x * 32 + threadIdx.x;
    int r0 = blockIdx.y * 32;
#pragma unroll
    for (int i = 0; i < 4; ++i) {
        int r = r0 + threadIdx.y + i * 8;
        tile[threadIdx.y + i * 8][threadIdx.x] = inp[(size_t)r * Cn + c];
    }
    __syncthreads();
    int oc = r0 + threadIdx.x; // output col = input row (k)
#pragma unroll
    for (int i = 0; i < 4; ++i) {
        int orow = blockIdx.x * 32 + threadIdx.y + i * 8; // output row (n)
        outp[(size_t)orow * R + oc] = f2bf(tile[threadIdx.x][threadIdx.y + i * 8]);
    }
}

// ---------------- embedding ----------------
__global__ __launch_bounds__(256) void embed_kernel(const int* __restrict__ idx,
                                                    const float* __restrict__ wte,
                                                    const float* __restrict__ wpe,
                                                    float* __restrict__ h) {
    int row = blockIdx.x;          // 0..2047
    int s   = row & (SS - 1);
    int tok = idx[row];
    const float* we = wte + (size_t)tok * CC;
    const float* pe = wpe + (size_t)s * CC;
    float* hr = h + (size_t)row * CC;
    for (int c = threadIdx.x; c < CC; c += 256) hr[c] = we[c] + pe[c];
}

// ---------------- layernorm: f32 in -> bf16 out ----------------
__global__ __launch_bounds__(256) void ln_kernel(const float* __restrict__ h,
                                                 const float* __restrict__ w,
                                                 const float* __restrict__ b,
                                                 u16* __restrict__ x) {
    int row = blockIdx.x, tid = threadIdx.x;
    const float* hr = h + (size_t)row * CC;
    float v0 = hr[tid], v1 = hr[tid + 256], v2 = hr[tid + 512];
    float s  = v0 + v1 + v2;
    float s2 = v0 * v0 + v1 * v1 + v2 * v2;
#pragma unroll
    for (int off = 32; off; off >>= 1) {
        s  += __shfl_xor(s, off);
        s2 += __shfl_xor(s2, off);
    }
    __shared__ float rs[4], rs2[4], stat[2];
    int wid = tid >> 6;
    if ((tid & 63) == 0) { rs[wid] = s; rs2[wid] = s2; }
    __syncthreads();
    if (tid == 0) {
        float ts  = rs[0] + rs[1] + rs[2] + rs[3];
        float ts2 = rs2[0] + rs2[1] + rs2[2] + rs2[3];
        float mean = ts * (1.0f / CC);
        float var  = ts2 * (1.0f / CC) - mean * mean;
        stat[0] = mean;
        stat[1] = rsqrtf(var + 1e-5f);
    }
    __syncthreads();
    float mean = stat[0], rstd = stat[1];
    size_t base = (size_t)row * CC;
    x[base + tid]       = f2bf((v0 - mean) * rstd * w[tid]       + b[tid]);
    x[base + tid + 256] = f2bf((v1 - mean) * rstd * w[tid + 256] + b[tid + 256]);
    x[base + tid + 512] = f2bf((v2 - mean) * rstd * w[tid + 512] + b[tid + 512]);
}

// ---------------- GEMM: C[M,N] = A[M,K] @ Bt[N,K]^T  (bf16 in, f32 acc) ----------------
// EPI: 0 = bias -> bf16 out        (qkv)
//      1 = bias+gelu -> bf16 out   (fc)
//      2 = bias, residual add into f32 outf (proj, fc2)
//      3 = no bias, f32 out with col<nmax guard (lm_head)
template <int BM, int BN, int EPI>
__global__ __launch_bounds__((BM / 64) * (BN / 64) * 64)
void gemm_bt_kernel(const u16* __restrict__ A, const u16* __restrict__ Bt,
                    const float* __restrict__ bias, float* __restrict__ outf,
                    u16* __restrict__ outb, int K, long long ldo, int nmax) {
    constexpr int NWM = BM / 64, NWN = BN / 64;
    constexpr int THREADS = NWM * NWN * 64;
    __shared__ u16 As[BM * 64];
    __shared__ u16 Bs[BN * 64];
    const int tid  = threadIdx.x;
    const int lane = tid & 63;
    const int wid  = tid >> 6;
    const int wm   = wid % NWM;
    const int wn   = wid / NWM;
    const int bm0  = blockIdx.y * BM;
    const int bn0  = blockIdx.x * BN;
    const int l15  = lane & 15;
    const int lq   = lane >> 4;

    f32x4 acc[4][4];
#pragma unroll
    for (int m = 0; m < 4; ++m)
#pragma unroll
        for (int n = 0; n < 4; ++n) acc[m][n] = (f32x4){0.f, 0.f, 0.f, 0.f};

    for (int kt = 0; kt < K; kt += 64) {
        // stage A tile [BM][64], B tile [BN][64] (reg-staged)
#pragma unroll
        for (int it = 0; it < BM * 64 / (THREADS * 8); ++it) {
            int e = (it * THREADS + tid) * 8;
            int r = e >> 6, c = e & 63;
            *(u16x8*)&As[e] = *(const u16x8*)&A[(size_t)(bm0 + r) * K + kt + c];
        }
#pragma unroll
        for (int it = 0; it < BN * 64 / (THREADS * 8); ++it) {
            int e = (it * THREADS + tid) * 8;
            int r = e >> 6, c = e & 63;
            *(u16x8*)&Bs[e] = *(const u16x8*)&Bt[(size_t)(bn0 + r) * K + kt + c];
        }
        __syncthreads();
#pragma unroll
        for (int ks = 0; ks < 2; ++ks) {
            s16x8 af[4], bfr[4];
#pragma unroll
            for (int m = 0; m < 4; ++m)
                af[m] = *(const s16x8*)&As[(wm * 64 + m * 16 + l15) * 64 + ks * 32 + lq * 8];
#pragma unroll
            for (int n = 0; n < 4; ++n)
                bfr[n] = *(const s16x8*)&Bs[(wn * 64 + n * 16 + l15) * 64 + ks * 32 + lq * 8];
#pragma unroll
            for (int m = 0; m < 4; ++m)
#pragma unroll
                for (int n = 0; n < 4; ++n)
                    acc[m][n] = __builtin_amdgcn_mfma_f32_16x16x32_bf16(af[m], bfr[n], acc[m][n], 0, 0, 0);
        }
        __syncthreads();
    }

    // epilogue: C/D layout col=lane&15, row=4*(lane>>4)+reg
#pragma unroll
    for (int m = 0; m < 4; ++m) {
#pragma unroll
        for (int n = 0; n < 4; ++n) {
#pragma unroll
            for (int r = 0; r < 4; ++r) {
                int row = bm0 + wm * 64 + m * 16 + lq * 4 + r;
                int col = bn0 + wn * 64 + n * 16 + l15;
                float v = acc[m][n][r];
                if (EPI != 3) v += bias[col];
                if (EPI == 1) {
                    float xg = v;
                    v = 0.5f * xg * (1.0f + tanhf(0.7978845608028654f * (xg + 0.044715f * xg * xg * xg)));
                }
                if (EPI == 0 || EPI == 1) {
                    outb[(size_t)row * ldo + col] = f2bf(v);
                } else if (EPI == 2) {
                    outf[(size_t)row * ldo + col] += v;
                } else {
                    if (col < nmax) outf[(size_t)row * ldo + col] = v;
                }
            }
        }
    }
}

// ---------------- MFMA flash attention ----------------
// One block = 64 query rows of one (b,h); 4 waves, each owns 16 rows.
// K-tiles of 64 keys staged in LDS; V staged transposed [d][t].
// grid.x = B*H*(S/64) = 384
__global__ __launch_bounds__(256) void attn_mfma_kernel(const u16* __restrict__ qkv,
                                                        u16* __restrict__ o) {
    constexpr int KB = 64, PADC = 72;
    __shared__ u16 Ks[KB][PADC];     // K[t][d]
    __shared__ u16 Vs[DD][PADC];     // V^T[d][t]
    __shared__ u16 Ps[4][16][PADC];  // per-wave P tile [row][t]

    const int tid = threadIdx.x, lane = tid & 63, wid = tid >> 6;
    const int l15 = lane & 15, lq = lane >> 4;
    const int blk = blockIdx.x;
    const int q0  = (blk & (SS / 64 - 1)) * 64;
    const int bh  = blk / (SS / 64);
    const int b   = bh / HH, hh = bh % HH;

    const size_t base = (size_t)b * SS * (3 * CC);
    const u16* qp = qkv + base + hh * DD;            // row stride 3C
    const u16* kp = qkv + base + CC + hh * DD;
    const u16* vp = qkv + base + 2 * CC + hh * DD;

    // Q fragments: row = q0 + wid*16 + l15, k(d) = ks*32 + lq*8
    s16x8 qf[2];
    {
        const u16* qr = qp + (size_t)(q0 + wid * 16 + l15) * (3 * CC);
        qf[0] = *(const s16x8*)&qr[lq * 8];
        qf[1] = *(const s16x8*)&qr[32 + lq * 8];
    }

    float m[4], lsum[4];
    f32x4 acc_o[4];
#pragma unroll
    for (int r = 0; r < 4; ++r) { m[r] = -3.0e38f; lsum[r] = 0.f; }
#pragma unroll
    for (int nd = 0; nd < 4; ++nd) acc_o[nd] = (f32x4){0.f, 0.f, 0.f, 0.f};

    const int tend = q0 + 64;  // causal: keys < q0+64
    for (int t0 = 0; t0 < tend; t0 += KB) {
        __syncthreads();  // previous iteration's Vs/Ks reads done
        // stage K tile [64][64] linear
#pragma unroll
        for (int it = 0; it < 2; ++it) {
            int g = it * 256 + tid;
            int t = g >> 3, dc = g & 7;
            *(u16x8*)&Ks[t][dc * 8] = *(const u16x8*)&kp[(size_t)(t0 + t) * (3 * CC) + dc * 8];
        }
        // stage V tile transposed: Vs[d][t]
#pragma unroll
        for (int it = 0; it < 2; ++it) {
            int g = it * 256 + tid;
            int t = g >> 3, dc = g & 7;
            u16x8 v = *(const u16x8*)&vp[(size_t)(t0 + t) * (3 * CC) + dc * 8];
#pragma unroll
            for (int e = 0; e < 8; ++e) Vs[dc * 8 + e][t] = v[e];
        }
        __syncthreads();

        // QK^T: S[16 rows][64 cols]
        f32x4 acc_s[4];
#pragma unroll
        for (int n = 0; n < 4; ++n) acc_s[n] = (f32x4){0.f, 0.f, 0.f, 0.f};
#pragma unroll
        for (int ks = 0; ks < 2; ++ks) {
#pragma unroll
            for (int n = 0; n < 4; ++n) {
                s16x8 kb = *(const s16x8*)&Ks[n * 16 + l15][ks * 32 + lq * 8];
                acc_s[n] = __builtin_amdgcn_mfma_f32_16x16x32_bf16(qf[ks], kb, acc_s[n], 0, 0, 0);
            }
        }

        // scale + causal mask (acc layout: row = lq*4+r, col = n*16+l15)
#pragma unroll
        for (int n = 0; n < 4; ++n) {
            int colg = t0 + n * 16 + l15;
#pragma unroll
            for (int r = 0; r < 4; ++r) {
                int rowg = q0 + wid * 16 + lq * 4 + r;
                float sv = acc_s[n][r] * 0.125f;
                acc_s[n][r] = (colg <= rowg) ? sv : -3.0e38f;
            }
        }
        // row max across 64 cols: local over n, then shfl over l15 group
        float mt[4];
#pragma unroll
        for (int r = 0; r < 4; ++r)
            mt[r] = fmaxf(fmaxf(acc_s[0][r], acc_s[1][r]), fmaxf(acc_s[2][r], acc_s[3][r]));
#pragma unroll
        for (int off = 1; off < 16; off <<= 1)
#pragma unroll
            for (int r = 0; r < 4; ++r) mt[r] = fmaxf(mt[r], __shfl_xor(mt[r], off));

        // online softmax update
        float rs[4];
#pragma unroll
        for (int r = 0; r < 4; ++r) {
            float mn  = fmaxf(m[r], mt[r]);
            float scl = __expf(m[r] - mn);
            m[r] = mn;
            float ps = 0.f;
#pragma unroll
            for (int n = 0; n < 4; ++n) {
                float p = __expf(acc_s[n][r] - mn);
                acc_s[n][r] = p;
                ps += p;
            }
            rs[r] = ps;
            lsum[r] *= scl;
#pragma unroll
            for (int nd = 0; nd < 4; ++nd) acc_o[nd][r] *= scl;
        }
#pragma unroll
        for (int off = 1; off < 16; off <<= 1)
#pragma unroll
            for (int r = 0; r < 4; ++r) rs[r] += __shfl_xor(rs[r], off);
#pragma unroll
        for (int r = 0; r < 4; ++r) lsum[r] += rs[r];

        // store P (bf16) to LDS in A-fragment-readable layout
#pragma unroll
        for (int n = 0; n < 4; ++n)
#pragma unroll
            for (int r = 0; r < 4; ++r)
                Ps[wid][lq * 4 + r][n * 16 + l15] = f2bf(acc_s[n][r]);
        __syncthreads();

        // PV: O[16 rows][64 d] += P[16][64t] * V[64t][64d]
#pragma unroll
        for (int ks = 0; ks < 2; ++ks) {
            s16x8 pa = *(const s16x8*)&Ps[wid][l15][ks * 32 + lq * 8];
#pragma unroll
            for (int nd = 0; nd < 4; ++nd) {
                s16x8 vb = *(const s16x8*)&Vs[nd * 16 + l15][ks * 32 + lq * 8];
                acc_o[nd] = __builtin_amdgcn_mfma_f32_16x16x32_bf16(pa, vb, acc_o[nd], 0, 0, 0);
            }
        }
    }

    // epilogue
#pragma unroll
    for (int r = 0; r < 4; ++r) {
        float inv = 1.f / lsum[r];
        int rowg = q0 + wid * 16 + lq * 4 + r;
        u16* orow = o + ((size_t)b * SS + rowg) * CC + hh * DD;
#pragma unroll
        for (int nd = 0; nd < 4; ++nd)
            orow[nd * 16 + l15] = f2bf(acc_o[nd][r] * inv);
    }
}

// ---------------- loss ----------------
__global__ __launch_bounds__(256) void lse_kernel(const float* __restrict__ logits,
                                                  const int* __restrict__ tgt,
                                                  float* __restrict__ lossp) {
    int row = blockIdx.x, tid = threadIdx.x;
    const float* lr = logits + (size_t)row * VV;
    float m = -3.0e38f, s = 0.f;
    for (int i = tid; i < VV; i += 256) {
        float x = lr[i];
        float nm = fmaxf(m, x);
        s = s * __expf(m - nm) + __expf(x - nm);
        m = nm;
    }
#pragma unroll
    for (int off = 32; off; off >>= 1) {
        float om = __shfl_xor(m, off), os = __shfl_xor(s, off);
        float nm = fmaxf(m, om);
        s = s * __expf(m - nm) + os * __expf(om - nm);
        m = nm;
    }
    __shared__ float rm[4], rsh[4];
    int wid = tid >> 6;
    if ((tid & 63) == 0) { rm[wid] = m; rsh[wid] = s; }
    __syncthreads();
    if (tid == 0) {
        float M = fmaxf(fmaxf(rm[0], rm[1]), fmaxf(rm[2], rm[3]));
        float S = rsh[0] * __expf(rm[0] - M) + rsh[1] * __expf(rm[1] - M) +
                  rsh[2] * __expf(rm[2] - M) + rsh[3] * __expf(rm[3] - M);
        float lse = M + __logf(S);
        lossp[row] = lse - lr[tgt[row]];
    }
}

__global__ __launch_bounds__(256) void loss_reduce_kernel(const float* __restrict__ lossp,
                                                          float* __restrict__ out) {
    int tid = threadIdx.x;
    float s = 0.f;
    for (int i = tid; i < MM; i += 256) s += lossp[i];
#pragma unroll
    for (int off = 32; off; off >>= 1) s += __shfl_xor(s, off);
    __shared__ float r[4];
    if ((tid & 63) == 0) r[tid >> 6] = s;
    __syncthreads();
    if (tid == 0) out[0] = (r[0] + r[1] + r[2] + r[3]) * (1.0f / MM);
}

// ---------------- host ----------------
extern "C" void kernel_launch(void* const* d_in, const int* in_sizes, int n_in,
                              void* d_out, int out_size, void* d_ws, size_t ws_size,
                              hipStream_t stream) {
    const int*   idx     = (const int*)  d_in[0];
    const int*   targets = (const int*)  d_in[1];
    const float* wte     = (const float*)d_in[2];
    const float* wpe     = (const float*)d_in[3];
    const float* ln1w    = (const float*)d_in[4];
    const float* ln1b    = (const float*)d_in[5];
    const float* qkvw    = (const float*)d_in[6];
    const float* qkvbi   = (const float*)d_in[7];
    const float* projw   = (const float*)d_in[8];
    const float* projbi  = (const float*)d_in[9];
    const float* ln2w    = (const float*)d_in[10];
    const float* ln2b    = (const float*)d_in[11];
    const float* fcw     = (const float*)d_in[12];
    const float* fcbi    = (const float*)d_in[13];
    const float* fc2w    = (const float*)d_in[14];
    const float* fc2bi   = (const float*)d_in[15];
    const float* lnfw    = (const float*)d_in[16];
    const float* lnfb    = (const float*)d_in[17];
    float* logits = (float*)d_out;

    char* wsb = (char*)d_ws;
    size_t off = 0;
    auto alloc = [&](size_t n) -> char* {
        char* p = wsb + off;
        off = (off + n + 255) & ~(size_t)255;
        return p;
    };
    u16*   wteT  = (u16*)  alloc((size_t)VPAD * CC * 2);
    u16*   qkvT  = (u16*)  alloc((size_t)LNUM * 3 * CC * CC * 2);
    u16*   projT = (u16*)  alloc((size_t)LNUM * CC * CC * 2);
    u16*   fcT   = (u16*)  alloc((size_t)LNUM * FFD * CC * 2);
    u16*   fc2T  = (u16*)  alloc((size_t)LNUM * CC * FFD * 2);
    float* h     = (float*)alloc((size_t)MM * CC * 4);
    u16*   xb    = (u16*)  alloc((size_t)MM * CC * 2);
    u16*   qkvb  = (u16*)  alloc((size_t)MM * 3 * CC * 2);
    u16*   ob    = (u16*)  alloc((size_t)MM * CC * 2);
    u16*   gb    = (u16*)  alloc((size_t)MM * FFD * 2);
    float* lossp = (float*)alloc((size_t)MM * 4);

    // weight prep
    {
        int blocks = (int)(((size_t)VPAD * CC / 4 + 255) / 256);
        wte_conv_kernel<<<blocks, 256, 0, stream>>>(wte, wteT);
    }
    transpose_conv_kernel<<<dim3(3 * CC / 32, CC / 32, LNUM), dim3(32, 8), 0, stream>>>(qkvw, qkvT, CC, 3 * CC);
    transpose_conv_kernel<<<dim3(CC / 32, CC / 32, LNUM),     dim3(32, 8), 0, stream>>>(projw, projT, CC, CC);
    transpose_conv_kernel<<<dim3(FFD / 32, CC / 32, LNUM),    dim3(32, 8), 0, stream>>>(fcw, fcT, CC, FFD);
    transpose_conv_kernel<<<dim3(CC / 32, FFD / 32, LNUM),    dim3(32, 8), 0, stream>>>(fc2w, fc2T, FFD, CC);

    embed_kernel<<<MM, 256, 0, stream>>>(idx, wte, wpe, h);

    for (int l = 0; l < LNUM; ++l) {
        const u16* qkvT_l  = qkvT  + (size_t)l * 3 * CC * CC;
        const u16* projT_l = projT + (size_t)l * CC * CC;
        const u16* fcT_l   = fcT   + (size_t)l * FFD * CC;
        const u16* fc2T_l  = fc2T  + (size_t)l * CC * FFD;

        ln_kernel<<<MM, 256, 0, stream>>>(h, ln1w + (size_t)l * CC, ln1b + (size_t)l * CC, xb);
        gemm_bt_kernel<128, 128, 0><<<dim3(3 * CC / 128, MM / 128), 256, 0, stream>>>(
            xb, qkvT_l, qkvbi + (size_t)l * 3 * CC, nullptr, qkvb, CC, 3 * CC, 0);
        attn_mfma_kernel<<<BB * HH * (SS / 64), 256, 0, stream>>>(qkvb, ob);
        gemm_bt_kernel<64, 64, 2><<<dim3(CC / 64, MM / 64), 64, 0, stream>>>(
            ob, projT_l, projbi + (size_t)l * CC, h, nullptr, CC, CC, 0);
        ln_kernel<<<MM, 256, 0, stream>>>(h, ln2w + (size_t)l * CC, ln2b + (size_t)l * CC, xb);
        gemm_bt_kernel<128, 128, 1><<<dim3(FFD / 128, MM / 128), 256, 0, stream>>>(
            xb, fcT_l, fcbi + (size_t)l * FFD, nullptr, gb, CC, FFD, 0);
        gemm_bt_kernel<64, 64, 2><<<dim3(CC / 64, MM / 64), 64, 0, stream>>>(
            gb, fc2T_l, fc2bi + (size_t)l * CC, h, nullptr, FFD, CC, 0);
    }

    ln_kernel<<<MM, 256, 0, stream>>>(h, lnfw, lnfb, xb);
    gemm_bt_kernel<128, 128, 3><<<dim3(VPAD / 128, MM / 128), 256, 0, stream>>>(
        xb, wteT, nullptr, logits, nullptr, CC, VV, VV);

    lse_kernel<<<MM, 256, 0, stream>>>(logits, targets, lossp);
    loss_reduce_kernel<<<1, 256, 0, stream>>>(lossp, logits + (size_t)MM * VV);
}

// Round 3
// 2718.719 us; speedup vs baseline: 2.4798x; 1.1163x over previous
//
#include <hip/hip_runtime.h>
#include <hip/hip_bf16.h>
#include <cstdint>
#include <cstddef>

// ---- model dims ----
constexpr int LNUM = 12;
constexpr int BB   = 2;
constexpr int SS   = 1024;
constexpr int CC   = 768;
constexpr int HH   = 12;
constexpr int DD   = 64;      // C/H
constexpr int FFD  = 3072;    // 4C
constexpr int VV   = 50257;
constexpr int VPAD = 50304;   // V rounded up to 128
constexpr int MM   = BB * SS; // 2048 token rows
constexpr int NBX  = VPAD / 128; // lm_head col-blocks = 393

typedef unsigned short u16;
typedef short     s16x8 __attribute__((ext_vector_type(8)));
typedef float     f32x4 __attribute__((ext_vector_type(4)));
typedef u16       u16x4 __attribute__((ext_vector_type(4)));
typedef u16       u16x8 __attribute__((ext_vector_type(8)));

__device__ __forceinline__ float bf2f(u16 v) {
    return __uint_as_float(((unsigned)v) << 16);
}
__device__ __forceinline__ u16 f2bf(float f) {
    unsigned u = __float_as_uint(f);
    return (u16)((u + 0x7fffu + ((u >> 16) & 1u)) >> 16);
}

// async global->LDS, 16 B per lane; LDS dest = wave-uniform base + lane*16
__device__ __forceinline__ void gload16(const u16* g, u16* l) {
    __builtin_amdgcn_global_load_lds(
        (const __attribute__((address_space(1))) unsigned int*)g,
        (__attribute__((address_space(3))) unsigned int*)l,
        16, 0, 0);
}

// ---------------- weight prep ----------------

// wte [V][C] f32 -> bf16 [VPAD][C], pad rows zero
__global__ __launch_bounds__(256) void wte_conv_kernel(const float* __restrict__ wte,
                                                       u16* __restrict__ out) {
    size_t i4 = ((size_t)blockIdx.x * 256 + threadIdx.x) * 4;
    if (i4 >= (size_t)VPAD * CC) return;
    size_t r = i4 / CC;
    u16x4 o;
    if (r < (size_t)VV) {
        const float4 v = *(const float4*)&wte[i4];
        o[0] = f2bf(v.x); o[1] = f2bf(v.y); o[2] = f2bf(v.z); o[3] = f2bf(v.w);
    } else {
        o[0] = o[1] = o[2] = o[3] = 0;
    }
    *(u16x4*)&out[i4] = o;
}

// in: [L][R][Cn] f32   out: [L][Cn][R] bf16   (R,Cn multiples of 32)
__global__ __launch_bounds__(256) void transpose_conv_kernel(const float* __restrict__ in,
                                                             u16* __restrict__ out,
                                                             int R, int Cn) {
    __shared__ float tile[32][33];
    const float* inp = in + (size_t)blockIdx.z * R * Cn;
    u16* outp = out + (size_t)blockIdx.z * R * Cn;
    int c  = blockIdx.x * 32 + threadIdx.x;
    int r0 = blockIdx.y * 32;
#pragma unroll
    for (int i = 0; i < 4; ++i) {
        int r = r0 + threadIdx.y + i * 8;
        tile[threadIdx.y + i * 8][threadIdx.x] = inp[(size_t)r * Cn + c];
    }
    __syncthreads();
    int oc = r0 + threadIdx.x; // output col = input row (k)
#pragma unroll
    for (int i = 0; i < 4; ++i) {
        int orow = blockIdx.x * 32 + threadIdx.y + i * 8; // output row (n)
        outp[(size_t)orow * R + oc] = f2bf(tile[threadIdx.x][threadIdx.y + i * 8]);
    }
}

// ---------------- embedding ----------------
__global__ __launch_bounds__(256) void embed_kernel(const int* __restrict__ idx,
                                                    const float* __restrict__ wte,
                                                    const float* __restrict__ wpe,
                                                    float* __restrict__ h) {
    int row = blockIdx.x;          // 0..2047
    int s   = row & (SS - 1);
    int tok = idx[row];
    const float* we = wte + (size_t)tok * CC;
    const float* pe = wpe + (size_t)s * CC;
    float* hr = h + (size_t)row * CC;
    for (int c = threadIdx.x; c < CC; c += 256) hr[c] = we[c] + pe[c];
}

// ---------------- layernorm: f32 in -> bf16 out ----------------
__global__ __launch_bounds__(256) void ln_kernel(const float* __restrict__ h,
                                                 const float* __restrict__ w,
                                                 const float* __restrict__ b,
                                                 u16* __restrict__ x) {
    int row = blockIdx.x, tid = threadIdx.x;
    const float* hr = h + (size_t)row * CC;
    float v0 = hr[tid], v1 = hr[tid + 256], v2 = hr[tid + 512];
    float s  = v0 + v1 + v2;
    float s2 = v0 * v0 + v1 * v1 + v2 * v2;
#pragma unroll
    for (int off = 32; off; off >>= 1) {
        s  += __shfl_xor(s, off);
        s2 += __shfl_xor(s2, off);
    }
    __shared__ float rs[4], rs2[4], stat[2];
    int wid = tid >> 6;
    if ((tid & 63) == 0) { rs[wid] = s; rs2[wid] = s2; }
    __syncthreads();
    if (tid == 0) {
        float ts  = rs[0] + rs[1] + rs[2] + rs[3];
        float ts2 = rs2[0] + rs2[1] + rs2[2] + rs2[3];
        float mean = ts * (1.0f / CC);
        float var  = ts2 * (1.0f / CC) - mean * mean;
        stat[0] = mean;
        stat[1] = rsqrtf(var + 1e-5f);
    }
    __syncthreads();
    float mean = stat[0], rstd = stat[1];
    size_t base = (size_t)row * CC;
    x[base + tid]       = f2bf((v0 - mean) * rstd * w[tid]       + b[tid]);
    x[base + tid + 256] = f2bf((v1 - mean) * rstd * w[tid + 256] + b[tid + 256]);
    x[base + tid + 512] = f2bf((v2 - mean) * rstd * w[tid + 512] + b[tid + 512]);
}

// ---------------- GEMM: C[M,N] = A[M,K] @ Bt[N,K]^T  (bf16 in, f32 acc) ----------------
// m97 structure: global_load_lds staging, linear LDS, 2-barrier K-loop,
// 4 waves/block, wave tile (BM/2)x(BN/2). XCD-chunked block swizzle with
// column-major work ids so consecutive work ids share a B-panel.
// EPI: 0 = bias -> bf16 out        (qkv)
//      1 = bias+gelu -> bf16 out   (fc)
//      2 = bias, residual add into f32 outf (proj, fc2)
//      3 = no bias, f32 logits out (col<VV) + per-block lse partials (lm_head)
template <int BM, int BN, int EPI>
__global__ __launch_bounds__(256)
void gemm_bt_kernel(const u16* __restrict__ A, const u16* __restrict__ Bt,
                    const float* __restrict__ bias, float* __restrict__ outf,
                    u16* __restrict__ outb, int K, long long ldo,
                    float* __restrict__ partM, float* __restrict__ partS) {
    constexpr int MR = BM / 32, NR = BN / 32; // fragment repeats AND staging instrs/wave
    __shared__ u16 As[BM * 64];
    __shared__ u16 Bs[BN * 64];
    const int tid  = threadIdx.x;
    const int lane = tid & 63;
    const int wid  = tid >> 6;
    const int l15  = lane & 15;
    const int lq   = lane >> 4;
    const int sub  = lane >> 3;
    const int cl8  = (lane & 7) * 8;
    const int wm   = wid & 1;
    const int wn   = wid >> 1;

    // XCD-chunked bijective remap; work id is column-major (bx outer, by inner)
    const int gx = gridDim.x, gy = gridDim.y;
    const int nwg = gx * gy;
    const int pos = blockIdx.y * gx + blockIdx.x;      // dispatch order
    const int qc  = nwg >> 3, rc = nwg & 7;
    const int xcd = pos & 7, cidx = pos >> 3;
    const int wgid = (xcd < rc ? xcd * (qc + 1) : rc * (qc + 1) + (xcd - rc) * qc) + cidx;
    const int bx = wgid / gy, by = wgid % gy;
    const int bm0 = by * BM, bn0 = bx * BN;

    f32x4 acc[MR][NR];
#pragma unroll
    for (int m = 0; m < MR; ++m)
#pragma unroll
        for (int n = 0; n < NR; ++n) acc[m][n] = (f32x4){0.f, 0.f, 0.f, 0.f};

    for (int kt = 0; kt < K; kt += 64) {
        __syncthreads(); // previous compute done before overwriting LDS
#pragma unroll
        for (int i = 0; i < MR; ++i) {
            int rw = (i * 4 + wid) * 8 + sub;
            gload16(&A[(size_t)(bm0 + rw) * (size_t)K + kt + cl8], &As[(i * 4 + wid) * 512]);
        }
#pragma unroll
        for (int i = 0; i < NR; ++i) {
            int rw = (i * 4 + wid) * 8 + sub;
            gload16(&Bt[(size_t)(bn0 + rw) * (size_t)K + kt + cl8], &Bs[(i * 4 + wid) * 512]);
        }
        __syncthreads(); // vmcnt(0) drained by barrier -> LDS ready
#pragma unroll
        for (int ks = 0; ks < 2; ++ks) {
            s16x8 af[MR], bfr[NR];
#pragma unroll
            for (int m = 0; m < MR; ++m)
                af[m] = *(const s16x8*)&As[(wm * (BM / 2) + m * 16 + l15) * 64 + ks * 32 + lq * 8];
#pragma unroll
            for (int n = 0; n < NR; ++n)
                bfr[n] = *(const s16x8*)&Bs[(wn * (BN / 2) + n * 16 + l15) * 64 + ks * 32 + lq * 8];
#pragma unroll
            for (int m = 0; m < MR; ++m)
#pragma unroll
                for (int n = 0; n < NR; ++n)
                    acc[m][n] = __builtin_amdgcn_mfma_f32_16x16x32_bf16(af[m], bfr[n], acc[m][n], 0, 0, 0);
        }
    }

    // epilogue: C/D layout col=lane&15, row=4*(lane>>4)+reg
#pragma unroll
    for (int m = 0; m < MR; ++m) {
#pragma unroll
        for (int n = 0; n < NR; ++n) {
#pragma unroll
            for (int r = 0; r < 4; ++r) {
                int row = bm0 + wm * (BM / 2) + m * 16 + lq * 4 + r;
                int col = bn0 + wn * (BN / 2) + n * 16 + l15;
                float v = acc[m][n][r];
                if (EPI != 3) v += bias[col];
                if (EPI == 1) {
                    float xg = v;
                    v = 0.5f * xg * (1.0f + tanhf(0.7978845608028654f * (xg + 0.044715f * xg * xg * xg)));
                }
                if (EPI == 0 || EPI == 1) {
                    outb[(size_t)row * ldo + col] = f2bf(v);
                } else if (EPI == 2) {
                    outf[(size_t)row * ldo + col] += v;
                } else {
                    if (col < VV) outf[(size_t)row * ldo + col] = v;
                }
            }
        }
    }

    // lm_head: per-row partial logsumexp over this block's BN cols
    if constexpr (EPI == 3) {
        __shared__ float redM[2][BM], redS[2][BM];
#pragma unroll
        for (int m = 0; m < MR; ++m) {
#pragma unroll
            for (int r = 0; r < 4; ++r) {
                float mx = -3.0e38f;
#pragma unroll
                for (int n = 0; n < NR; ++n) {
                    int colg = bn0 + wn * (BN / 2) + n * 16 + l15;
                    float v = (colg < VV) ? acc[m][n][r] : -3.0e38f;
                    mx = fmaxf(mx, v);
                }
#pragma unroll
                for (int off = 1; off < 16; off <<= 1) mx = fmaxf(mx, __shfl_xor(mx, off));
                float sm = 0.f;
#pragma unroll
                for (int n = 0; n < NR; ++n) {
                    int colg = bn0 + wn * (BN / 2) + n * 16 + l15;
                    if (colg < VV) sm += __expf(acc[m][n][r] - mx);
                }
#pragma unroll
                for (int off = 1; off < 16; off <<= 1) sm += __shfl_xor(sm, off);
                if (l15 == 0) {
                    int rl = wm * (BM / 2) + m * 16 + lq * 4 + r;
                    redM[wn][rl] = mx;
                    redS[wn][rl] = sm;
                }
            }
        }
        __syncthreads();
        if (tid < BM) {
            float m0 = redM[0][tid], m1 = redM[1][tid];
            float M = fmaxf(m0, m1);
            float S = redS[0][tid] * __expf(m0 - M) + redS[1][tid] * __expf(m1 - M);
            size_t rowg = (size_t)(bm0 + tid);
            partM[rowg * NBX + bx] = M;
            partS[rowg * NBX + bx] = S;
        }
    }
}

// ---------------- MFMA flash attention ----------------
// One block = 64 query rows of one (b,h); 4 waves, each owns 16 rows.
__global__ __launch_bounds__(256) void attn_mfma_kernel(const u16* __restrict__ qkv,
                                                        u16* __restrict__ o) {
    constexpr int KB = 64, PADC = 72;
    __shared__ u16 Ks[KB][PADC];     // K[t][d]
    __shared__ u16 Vs[DD][PADC];     // V^T[d][t]
    __shared__ u16 Ps[4][16][PADC];  // per-wave P tile [row][t]

    const int tid = threadIdx.x, lane = tid & 63, wid = tid >> 6;
    const int l15 = lane & 15, lq = lane >> 4;
    const int blk = blockIdx.x;
    const int q0  = (blk & (SS / 64 - 1)) * 64;
    const int bh  = blk / (SS / 64);
    const int b   = bh / HH, hh = bh % HH;

    const size_t base = (size_t)b * SS * (3 * CC);
    const u16* qp = qkv + base + hh * DD;            // row stride 3C
    const u16* kp = qkv + base + CC + hh * DD;
    const u16* vp = qkv + base + 2 * CC + hh * DD;

    s16x8 qf[2];
    {
        const u16* qr = qp + (size_t)(q0 + wid * 16 + l15) * (3 * CC);
        qf[0] = *(const s16x8*)&qr[lq * 8];
        qf[1] = *(const s16x8*)&qr[32 + lq * 8];
    }

    float m[4], lsum[4];
    f32x4 acc_o[4];
#pragma unroll
    for (int r = 0; r < 4; ++r) { m[r] = -3.0e38f; lsum[r] = 0.f; }
#pragma unroll
    for (int nd = 0; nd < 4; ++nd) acc_o[nd] = (f32x4){0.f, 0.f, 0.f, 0.f};

    const int tend = q0 + 64;
    for (int t0 = 0; t0 < tend; t0 += KB) {
        __syncthreads();
#pragma unroll
        for (int it = 0; it < 2; ++it) {
            int g = it * 256 + tid;
            int t = g >> 3, dc = g & 7;
            *(u16x8*)&Ks[t][dc * 8] = *(const u16x8*)&kp[(size_t)(t0 + t) * (3 * CC) + dc * 8];
        }
#pragma unroll
        for (int it = 0; it < 2; ++it) {
            int g = it * 256 + tid;
            int t = g >> 3, dc = g & 7;
            u16x8 v = *(const u16x8*)&vp[(size_t)(t0 + t) * (3 * CC) + dc * 8];
#pragma unroll
            for (int e = 0; e < 8; ++e) Vs[dc * 8 + e][t] = v[e];
        }
        __syncthreads();

        f32x4 acc_s[4];
#pragma unroll
        for (int n = 0; n < 4; ++n) acc_s[n] = (f32x4){0.f, 0.f, 0.f, 0.f};
#pragma unroll
        for (int ks = 0; ks < 2; ++ks) {
#pragma unroll
            for (int n = 0; n < 4; ++n) {
                s16x8 kb = *(const s16x8*)&Ks[n * 16 + l15][ks * 32 + lq * 8];
                acc_s[n] = __builtin_amdgcn_mfma_f32_16x16x32_bf16(qf[ks], kb, acc_s[n], 0, 0, 0);
            }
        }

#pragma unroll
        for (int n = 0; n < 4; ++n) {
            int colg = t0 + n * 16 + l15;
#pragma unroll
            for (int r = 0; r < 4; ++r) {
                int rowg = q0 + wid * 16 + lq * 4 + r;
                float sv = acc_s[n][r] * 0.125f;
                acc_s[n][r] = (colg <= rowg) ? sv : -3.0e38f;
            }
        }
        float mt[4];
#pragma unroll
        for (int r = 0; r < 4; ++r)
            mt[r] = fmaxf(fmaxf(acc_s[0][r], acc_s[1][r]), fmaxf(acc_s[2][r], acc_s[3][r]));
#pragma unroll
        for (int off = 1; off < 16; off <<= 1)
#pragma unroll
            for (int r = 0; r < 4; ++r) mt[r] = fmaxf(mt[r], __shfl_xor(mt[r], off));

        float rs[4];
#pragma unroll
        for (int r = 0; r < 4; ++r) {
            float mn  = fmaxf(m[r], mt[r]);
            float scl = __expf(m[r] - mn);
            m[r] = mn;
            float ps = 0.f;
#pragma unroll
            for (int n = 0; n < 4; ++n) {
                float p = __expf(acc_s[n][r] - mn);
                acc_s[n][r] = p;
                ps += p;
            }
            rs[r] = ps;
            lsum[r] *= scl;
#pragma unroll
            for (int nd = 0; nd < 4; ++nd) acc_o[nd][r] *= scl;
        }
#pragma unroll
        for (int off = 1; off < 16; off <<= 1)
#pragma unroll
            for (int r = 0; r < 4; ++r) rs[r] += __shfl_xor(rs[r], off);
#pragma unroll
        for (int r = 0; r < 4; ++r) lsum[r] += rs[r];

#pragma unroll
        for (int n = 0; n < 4; ++n)
#pragma unroll
            for (int r = 0; r < 4; ++r)
                Ps[wid][lq * 4 + r][n * 16 + l15] = f2bf(acc_s[n][r]);
        __syncthreads();

#pragma unroll
        for (int ks = 0; ks < 2; ++ks) {
            s16x8 pa = *(const s16x8*)&Ps[wid][l15][ks * 32 + lq * 8];
#pragma unroll
            for (int nd = 0; nd < 4; ++nd) {
                s16x8 vb = *(const s16x8*)&Vs[nd * 16 + l15][ks * 32 + lq * 8];
                acc_o[nd] = __builtin_amdgcn_mfma_f32_16x16x32_bf16(pa, vb, acc_o[nd], 0, 0, 0);
            }
        }
    }

#pragma unroll
    for (int r = 0; r < 4; ++r) {
        float inv = 1.f / lsum[r];
        int rowg = q0 + wid * 16 + lq * 4 + r;
        u16* orow = o + ((size_t)b * SS + rowg) * CC + hh * DD;
#pragma unroll
        for (int nd = 0; nd < 4; ++nd)
            orow[nd * 16 + l15] = f2bf(acc_o[nd][r] * inv);
    }
}

// ---------------- loss (from lm_head partials) ----------------
__global__ __launch_bounds__(256) void lse_kernel(const float* __restrict__ partM,
                                                  const float* __restrict__ partS,
                                                  const float* __restrict__ logits,
                                                  const int* __restrict__ tgt,
                                                  float* __restrict__ lossp) {
    int row = blockIdx.x, tid = threadIdx.x;
    float m = -3.0e38f, s = 0.f;
    for (int i = tid; i < NBX; i += 256) {
        float pm = partM[(size_t)row * NBX + i];
        float ps = partS[(size_t)row * NBX + i];
        float nm = fmaxf(m, pm);
        s = s * __expf(m - nm) + ps * __expf(pm - nm);
        m = nm;
    }
#pragma unroll
    for (int off = 32; off; off >>= 1) {
        float om = __shfl_xor(m, off), os = __shfl_xor(s, off);
        float nm = fmaxf(m, om);
        s = s * __expf(m - nm) + os * __expf(om - nm);
        m = nm;
    }
    __shared__ float rm[4], rsh[4];
    int wid = tid >> 6;
    if ((tid & 63) == 0) { rm[wid] = m; rsh[wid] = s; }
    __syncthreads();
    if (tid == 0) {
        float M = fmaxf(fmaxf(rm[0], rm[1]), fmaxf(rm[2], rm[3]));
        float S = rsh[0] * __expf(rm[0] - M) + rsh[1] * __expf(rm[1] - M) +
                  rsh[2] * __expf(rm[2] - M) + rsh[3] * __expf(rm[3] - M);
        float lse = M + __logf(S);
        lossp[row] = lse - logits[(size_t)row * VV + tgt[row]];
    }
}

__global__ __launch_bounds__(256) void loss_reduce_kernel(const float* __restrict__ lossp,
                                                          float* __restrict__ out) {
    int tid = threadIdx.x;
    float s = 0.f;
    for (int i = tid; i < MM; i += 256) s += lossp[i];
#pragma unroll
    for (int off = 32; off; off >>= 1) s += __shfl_xor(s, off);
    __shared__ float r[4];
    if ((tid & 63) == 0) r[tid >> 6] = s;
    __syncthreads();
    if (tid == 0) out[0] = (r[0] + r[1] + r[2] + r[3]) * (1.0f / MM);
}

// ---------------- host ----------------
extern "C" void kernel_launch(void* const* d_in, const int* in_sizes, int n_in,
                              void* d_out, int out_size, void* d_ws, size_t ws_size,
                              hipStream_t stream) {
    const int*   idx     = (const int*)  d_in[0];
    const int*   targets = (const int*)  d_in[1];
    const float* wte     = (const float*)d_in[2];
    const float* wpe     = (const float*)d_in[3];
    const float* ln1w    = (const float*)d_in[4];
    const float* ln1b    = (const float*)d_in[5];
    const float* qkvw    = (const float*)d_in[6];
    const float* qkvbi   = (const float*)d_in[7];
    const float* projw   = (const float*)d_in[8];
    const float* projbi  = (const float*)d_in[9];
    const float* ln2w    = (const float*)d_in[10];
    const float* ln2b    = (const float*)d_in[11];
    const float* fcw     = (const float*)d_in[12];
    const float* fcbi    = (const float*)d_in[13];
    const float* fc2w    = (const float*)d_in[14];
    const float* fc2bi   = (const float*)d_in[15];
    const float* lnfw    = (const float*)d_in[16];
    const float* lnfb    = (const float*)d_in[17];
    float* logits = (float*)d_out;

    char* wsb = (char*)d_ws;
    size_t off = 0;
    auto alloc = [&](size_t n) -> char* {
        char* p = wsb + off;
        off = (off + n + 255) & ~(size_t)255;
        return p;
    };
    u16*   wteT  = (u16*)  alloc((size_t)VPAD * CC * 2);
    u16*   qkvT  = (u16*)  alloc((size_t)LNUM * 3 * CC * CC * 2);
    u16*   projT = (u16*)  alloc((size_t)LNUM * CC * CC * 2);
    u16*   fcT   = (u16*)  alloc((size_t)LNUM * FFD * CC * 2);
    u16*   fc2T  = (u16*)  alloc((size_t)LNUM * CC * FFD * 2);
    float* h     = (float*)alloc((size_t)MM * CC * 4);
    u16*   xb    = (u16*)  alloc((size_t)MM * CC * 2);
    u16*   qkvb  = (u16*)  alloc((size_t)MM * 3 * CC * 2);
    u16*   ob    = (u16*)  alloc((size_t)MM * CC * 2);
    u16*   gb    = (u16*)  alloc((size_t)MM * FFD * 2);
    float* lossp = (float*)alloc((size_t)MM * 4);
    float* partM = (float*)alloc((size_t)MM * NBX * 4);
    float* partS = (float*)alloc((size_t)MM * NBX * 4);

    // weight prep
    {
        int blocks = (int)(((size_t)VPAD * CC / 4 + 255) / 256);
        wte_conv_kernel<<<blocks, 256, 0, stream>>>(wte, wteT);
    }
    transpose_conv_kernel<<<dim3(3 * CC / 32, CC / 32, LNUM), dim3(32, 8), 0, stream>>>(qkvw, qkvT, CC, 3 * CC);
    transpose_conv_kernel<<<dim3(CC / 32, CC / 32, LNUM),     dim3(32, 8), 0, stream>>>(projw, projT, CC, CC);
    transpose_conv_kernel<<<dim3(FFD / 32, CC / 32, LNUM),    dim3(32, 8), 0, stream>>>(fcw, fcT, CC, FFD);
    transpose_conv_kernel<<<dim3(CC / 32, FFD / 32, LNUM),    dim3(32, 8), 0, stream>>>(fc2w, fc2T, FFD, CC);

    embed_kernel<<<MM, 256, 0, stream>>>(idx, wte, wpe, h);

    for (int l = 0; l < LNUM; ++l) {
        const u16* qkvT_l  = qkvT  + (size_t)l * 3 * CC * CC;
        const u16* projT_l = projT + (size_t)l * CC * CC;
        const u16* fcT_l   = fcT   + (size_t)l * FFD * CC;
        const u16* fc2T_l  = fc2T  + (size_t)l * CC * FFD;

        ln_kernel<<<MM, 256, 0, stream>>>(h, ln1w + (size_t)l * CC, ln1b + (size_t)l * CC, xb);
        gemm_bt_kernel<128, 128, 0><<<dim3(3 * CC / 128, MM / 128), 256, 0, stream>>>(
            xb, qkvT_l, qkvbi + (size_t)l * 3 * CC, nullptr, qkvb, CC, 3 * CC, nullptr, nullptr);
        attn_mfma_kernel<<<BB * HH * (SS / 64), 256, 0, stream>>>(qkvb, ob);
        gemm_bt_kernel<64, 64, 2><<<dim3(CC / 64, MM / 64), 256, 0, stream>>>(
            ob, projT_l, projbi + (size_t)l * CC, h, nullptr, CC, CC, nullptr, nullptr);
        ln_kernel<<<MM, 256, 0, stream>>>(h, ln2w + (size_t)l * CC, ln2b + (size_t)l * CC, xb);
        gemm_bt_kernel<128, 128, 1><<<dim3(FFD / 128, MM / 128), 256, 0, stream>>>(
            xb, fcT_l, fcbi + (size_t)l * FFD, nullptr, gb, CC, FFD, nullptr, nullptr);
        gemm_bt_kernel<64, 64, 2><<<dim3(CC / 64, MM / 64), 256, 0, stream>>>(
            gb, fc2T_l, fc2bi + (size_t)l * CC, h, nullptr, FFD, CC, nullptr, nullptr);
    }

    ln_kernel<<<MM, 256, 0, stream>>>(h, lnfw, lnfb, xb);
    gemm_bt_kernel<128, 128, 3><<<dim3(VPAD / 128, MM / 128), 256, 0, stream>>>(
        xb, wteT, nullptr, logits, nullptr, CC, VV, partM, partS);

    lse_kernel<<<MM, 256, 0, stream>>>(partM, partS, logits, targets, lossp);
    loss_reduce_kernel<<<1, 256, 0, stream>>>(lossp, logits + (size_t)MM * VV);
}

// Round 4
// 2377.480 us; speedup vs baseline: 2.8357x; 1.1435x over previous
//
#include <hip/hip_runtime.h>
#include <hip/hip_bf16.h>
#include <cstdint>
#include <cstddef>

// ---- model dims ----
constexpr int LNUM = 12;
constexpr int BB   = 2;
constexpr int SS   = 1024;
constexpr int CC   = 768;
constexpr int HH   = 12;
constexpr int DD   = 64;      // C/H
constexpr int FFD  = 3072;    // 4C
constexpr int VV   = 50257;
constexpr int VPAD = 50304;   // V rounded up to 128
constexpr int MM   = BB * SS; // 2048 token rows
constexpr int NBX  = VPAD / 128; // lm_head col-blocks = 393

typedef unsigned short u16;
typedef short     s16x8 __attribute__((ext_vector_type(8)));
typedef float     f32x4 __attribute__((ext_vector_type(4)));
typedef u16       u16x4 __attribute__((ext_vector_type(4)));
typedef u16       u16x8 __attribute__((ext_vector_type(8)));

__device__ __forceinline__ float bf2f(u16 v) {
    return __uint_as_float(((unsigned)v) << 16);
}
__device__ __forceinline__ u16 f2bf(float f) {
    unsigned u = __float_as_uint(f);
    return (u16)((u + 0x7fffu + ((u >> 16) & 1u)) >> 16);
}

// async global->LDS, 16 B per lane; LDS dest = wave-uniform base + lane*16
__device__ __forceinline__ void gload16(const u16* g, u16* l) {
    __builtin_amdgcn_global_load_lds(
        (const __attribute__((address_space(1))) unsigned int*)g,
        (__attribute__((address_space(3))) unsigned int*)l,
        16, 0, 0);
}

// ---------------- weight prep ----------------

// wte [V][C] f32 -> bf16 [VPAD][C], pad rows zero
__global__ __launch_bounds__(256) void wte_conv_kernel(const float* __restrict__ wte,
                                                       u16* __restrict__ out) {
    size_t i4 = ((size_t)blockIdx.x * 256 + threadIdx.x) * 4;
    if (i4 >= (size_t)VPAD * CC) return;
    size_t r = i4 / CC;
    u16x4 o;
    if (r < (size_t)VV) {
        const float4 v = *(const float4*)&wte[i4];
        o[0] = f2bf(v.x); o[1] = f2bf(v.y); o[2] = f2bf(v.z); o[3] = f2bf(v.w);
    } else {
        o[0] = o[1] = o[2] = o[3] = 0;
    }
    *(u16x4*)&out[i4] = o;
}

// in: [L][R][Cn] f32   out: [L][Cn][R] bf16   (R,Cn multiples of 32)
__global__ __launch_bounds__(256) void transpose_conv_kernel(const float* __restrict__ in,
                                                             u16* __restrict__ out,
                                                             int R, int Cn) {
    __shared__ float tile[32][33];
    const float* inp = in + (size_t)blockIdx.z * R * Cn;
    u16* outp = out + (size_t)blockIdx.z * R * Cn;
    int c  = blockIdx.x * 32 + threadIdx.x;
    int r0 = blockIdx.y * 32;
#pragma unroll
    for (int i = 0; i < 4; ++i) {
        int r = r0 + threadIdx.y + i * 8;
        tile[threadIdx.y + i * 8][threadIdx.x] = inp[(size_t)r * Cn + c];
    }
    __syncthreads();
    int oc = r0 + threadIdx.x; // output col = input row (k)
#pragma unroll
    for (int i = 0; i < 4; ++i) {
        int orow = blockIdx.x * 32 + threadIdx.y + i * 8; // output row (n)
        outp[(size_t)orow * R + oc] = f2bf(tile[threadIdx.x][threadIdx.y + i * 8]);
    }
}

// ---------------- embedding ----------------
__global__ __launch_bounds__(256) void embed_kernel(const int* __restrict__ idx,
                                                    const float* __restrict__ wte,
                                                    const float* __restrict__ wpe,
                                                    float* __restrict__ h) {
    int row = blockIdx.x;          // 0..2047
    int s   = row & (SS - 1);
    int tok = idx[row];
    const float* we = wte + (size_t)tok * CC;
    const float* pe = wpe + (size_t)s * CC;
    float* hr = h + (size_t)row * CC;
    for (int c = threadIdx.x; c < CC; c += 256) hr[c] = we[c] + pe[c];
}

// ---------------- layernorm: f32 in -> bf16 out ----------------
__global__ __launch_bounds__(256) void ln_kernel(const float* __restrict__ h,
                                                 const float* __restrict__ w,
                                                 const float* __restrict__ b,
                                                 u16* __restrict__ x) {
    int row = blockIdx.x, tid = threadIdx.x;
    const float* hr = h + (size_t)row * CC;
    float v0 = hr[tid], v1 = hr[tid + 256], v2 = hr[tid + 512];
    float s  = v0 + v1 + v2;
    float s2 = v0 * v0 + v1 * v1 + v2 * v2;
#pragma unroll
    for (int off = 32; off; off >>= 1) {
        s  += __shfl_xor(s, off);
        s2 += __shfl_xor(s2, off);
    }
    __shared__ float rs[4], rs2[4], stat[2];
    int wid = tid >> 6;
    if ((tid & 63) == 0) { rs[wid] = s; rs2[wid] = s2; }
    __syncthreads();
    if (tid == 0) {
        float ts  = rs[0] + rs[1] + rs[2] + rs[3];
        float ts2 = rs2[0] + rs2[1] + rs2[2] + rs2[3];
        float mean = ts * (1.0f / CC);
        float var  = ts2 * (1.0f / CC) - mean * mean;
        stat[0] = mean;
        stat[1] = rsqrtf(var + 1e-5f);
    }
    __syncthreads();
    float mean = stat[0], rstd = stat[1];
    size_t base = (size_t)row * CC;
    x[base + tid]       = f2bf((v0 - mean) * rstd * w[tid]       + b[tid]);
    x[base + tid + 256] = f2bf((v1 - mean) * rstd * w[tid + 256] + b[tid + 256]);
    x[base + tid + 512] = f2bf((v2 - mean) * rstd * w[tid + 512] + b[tid + 512]);
}

// ---------------- GEMM: C[M,N] = A[M,K] @ Bt[N,K]^T  (bf16 in, f32 acc) ----------------
// Double-buffered gload_lds pipeline (T3-minimum): stage(next) -> compute(cur)
// -> vmcnt(0) -> s_barrier. One barrier per K-step; next-tile loads in flight
// across the MFMA section. LDS XOR chunk-swizzle (T2, both-sides): physical
// chunk = logical ^ (row&7); write side pre-swizzles the GLOBAL source (LDS
// dest stays linear per gload_lds), read side XORs the ds_read address.
// EPI: 0 = bias -> bf16 out        (qkv)
//      1 = bias+gelu -> bf16 out   (fc)
//      2 = bias, residual add into f32 outf (proj, fc2)
//      3 = no bias, f32 logits out (col<VV) + per-block lse partials (lm_head)
template <int BM, int BN, int EPI>
__global__ __launch_bounds__(256)
void gemm_bt_kernel(const u16* __restrict__ A, const u16* __restrict__ Bt,
                    const float* __restrict__ bias, float* __restrict__ outf,
                    u16* __restrict__ outb, int K, long long ldo,
                    float* __restrict__ partM, float* __restrict__ partS) {
    constexpr int MR = BM / 32, NR = BN / 32; // fragment repeats AND staging instrs/wave
    __shared__ u16 As0[BM * 64], Bs0[BN * 64];
    __shared__ u16 As1[BM * 64], Bs1[BN * 64];
    const int tid  = threadIdx.x;
    const int lane = tid & 63;
    const int wid  = tid >> 6;
    const int l15  = lane & 15;
    const int lq   = lane >> 4;
    const int sub  = lane >> 3;                 // row-within-8 this lane stages
    const int csw  = ((lane & 7) ^ sub) * 8;    // XOR-swizzled source chunk (u16)
    const int wm   = wid & 1;
    const int wn   = wid >> 1;
    const int rxor = (l15 & 7) * 8;             // read-side XOR term (u16)

    // XCD-chunked bijective remap; work id is column-major (bx outer, by inner)
    const int gx = gridDim.x, gy = gridDim.y;
    const int nwg = gx * gy;
    const int pos = blockIdx.y * gx + blockIdx.x;      // dispatch order
    const int qc  = nwg >> 3, rc = nwg & 7;
    const int xcd = pos & 7, cidx = pos >> 3;
    const int wgid = (xcd < rc ? xcd * (qc + 1) : rc * (qc + 1) + (xcd - rc) * qc) + cidx;
    const int bx = wgid / gy, by = wgid % gy;
    const int bm0 = by * BM, bn0 = bx * BN;

    f32x4 acc[MR][NR];
#pragma unroll
    for (int m = 0; m < MR; ++m)
#pragma unroll
        for (int n = 0; n < NR; ++n) acc[m][n] = (f32x4){0.f, 0.f, 0.f, 0.f};

    auto stage = [&](u16* Ad, u16* Bd, int kt) {
#pragma unroll
        for (int i = 0; i < MR; ++i) {
            int rw = (i * 4 + wid) * 8 + sub;
            gload16(&A[(size_t)(bm0 + rw) * (size_t)K + kt + csw], Ad + (i * 4 + wid) * 512);
        }
#pragma unroll
        for (int i = 0; i < NR; ++i) {
            int rw = (i * 4 + wid) * 8 + sub;
            gload16(&Bt[(size_t)(bn0 + rw) * (size_t)K + kt + csw], Bd + (i * 4 + wid) * 512);
        }
    };
    auto compute = [&](const u16* Ar, const u16* Br) {
#pragma unroll
        for (int ks = 0; ks < 2; ++ks) {
            s16x8 af[MR], bfr[NR];
#pragma unroll
            for (int m = 0; m < MR; ++m) {
                int row = wm * (BM / 2) + m * 16 + l15;
                af[m] = *(const s16x8*)&Ar[row * 64 + (((ks * 4 + lq) * 8) ^ rxor)];
            }
#pragma unroll
            for (int n = 0; n < NR; ++n) {
                int row = wn * (BN / 2) + n * 16 + l15;
                bfr[n] = *(const s16x8*)&Br[row * 64 + (((ks * 4 + lq) * 8) ^ rxor)];
            }
#pragma unroll
            for (int m = 0; m < MR; ++m)
#pragma unroll
                for (int n = 0; n < NR; ++n)
                    acc[m][n] = __builtin_amdgcn_mfma_f32_16x16x32_bf16(af[m], bfr[n], acc[m][n], 0, 0, 0);
        }
    };

    const int nk = K >> 6;  // always even here (12 or 48)
    stage(As0, Bs0, 0);
    asm volatile("s_waitcnt vmcnt(0)" ::: "memory");
    __builtin_amdgcn_s_barrier();
    for (int t = 0; t + 2 < nk; t += 2) {
        stage(As1, Bs1, (t + 1) << 6);
        compute(As0, Bs0);
        asm volatile("s_waitcnt vmcnt(0)" ::: "memory");
        __builtin_amdgcn_s_barrier();
        stage(As0, Bs0, (t + 2) << 6);
        compute(As1, Bs1);
        asm volatile("s_waitcnt vmcnt(0)" ::: "memory");
        __builtin_amdgcn_s_barrier();
    }
    stage(As1, Bs1, (nk - 1) << 6);
    compute(As0, Bs0);
    asm volatile("s_waitcnt vmcnt(0)" ::: "memory");
    __builtin_amdgcn_s_barrier();
    compute(As1, Bs1);

    // epilogue: C/D layout col=lane&15, row=4*(lane>>4)+reg
#pragma unroll
    for (int m = 0; m < MR; ++m) {
#pragma unroll
        for (int n = 0; n < NR; ++n) {
#pragma unroll
            for (int r = 0; r < 4; ++r) {
                int row = bm0 + wm * (BM / 2) + m * 16 + lq * 4 + r;
                int col = bn0 + wn * (BN / 2) + n * 16 + l15;
                float v = acc[m][n][r];
                if (EPI != 3) v += bias[col];
                if (EPI == 1) {
                    float xg = v;
                    v = 0.5f * xg * (1.0f + tanhf(0.7978845608028654f * (xg + 0.044715f * xg * xg * xg)));
                }
                if (EPI == 0 || EPI == 1) {
                    outb[(size_t)row * ldo + col] = f2bf(v);
                } else if (EPI == 2) {
                    outf[(size_t)row * ldo + col] += v;
                } else {
                    if (col < VV) outf[(size_t)row * ldo + col] = v;
                }
            }
        }
    }

    // lm_head: per-row partial logsumexp over this block's BN cols
    if constexpr (EPI == 3) {
        __shared__ float redM[2][BM], redS[2][BM];
#pragma unroll
        for (int m = 0; m < MR; ++m) {
#pragma unroll
            for (int r = 0; r < 4; ++r) {
                float mx = -3.0e38f;
#pragma unroll
                for (int n = 0; n < NR; ++n) {
                    int colg = bn0 + wn * (BN / 2) + n * 16 + l15;
                    float v = (colg < VV) ? acc[m][n][r] : -3.0e38f;
                    mx = fmaxf(mx, v);
                }
#pragma unroll
                for (int off = 1; off < 16; off <<= 1) mx = fmaxf(mx, __shfl_xor(mx, off));
                float sm = 0.f;
#pragma unroll
                for (int n = 0; n < NR; ++n) {
                    int colg = bn0 + wn * (BN / 2) + n * 16 + l15;
                    if (colg < VV) sm += __expf(acc[m][n][r] - mx);
                }
#pragma unroll
                for (int off = 1; off < 16; off <<= 1) sm += __shfl_xor(sm, off);
                if (l15 == 0) {
                    int rl = wm * (BM / 2) + m * 16 + lq * 4 + r;
                    redM[wn][rl] = mx;
                    redS[wn][rl] = sm;
                }
            }
        }
        __syncthreads();
        if (tid < BM) {
            float m0 = redM[0][tid], m1 = redM[1][tid];
            float M = fmaxf(m0, m1);
            float S = redS[0][tid] * __expf(m0 - M) + redS[1][tid] * __expf(m1 - M);
            size_t rowg = (size_t)(bm0 + tid);
            partM[rowg * NBX + bx] = M;
            partS[rowg * NBX + bx] = S;
        }
    }
}

// ---------------- MFMA flash attention ----------------
// One block = 64 query rows of one (b,h); 4 waves, each owns 16 rows.
__global__ __launch_bounds__(256) void attn_mfma_kernel(const u16* __restrict__ qkv,
                                                        u16* __restrict__ o) {
    constexpr int KB = 64, PADC = 72;
    __shared__ u16 Ks[KB][PADC];     // K[t][d]
    __shared__ u16 Vs[DD][PADC];     // V^T[d][t]
    __shared__ u16 Ps[4][16][PADC];  // per-wave P tile [row][t]

    const int tid = threadIdx.x, lane = tid & 63, wid = tid >> 6;
    const int l15 = lane & 15, lq = lane >> 4;
    const int blk = blockIdx.x;
    const int q0  = (blk & (SS / 64 - 1)) * 64;
    const int bh  = blk / (SS / 64);
    const int b   = bh / HH, hh = bh % HH;

    const size_t base = (size_t)b * SS * (3 * CC);
    const u16* qp = qkv + base + hh * DD;            // row stride 3C
    const u16* kp = qkv + base + CC + hh * DD;
    const u16* vp = qkv + base + 2 * CC + hh * DD;

    s16x8 qf[2];
    {
        const u16* qr = qp + (size_t)(q0 + wid * 16 + l15) * (3 * CC);
        qf[0] = *(const s16x8*)&qr[lq * 8];
        qf[1] = *(const s16x8*)&qr[32 + lq * 8];
    }

    float m[4], lsum[4];
    f32x4 acc_o[4];
#pragma unroll
    for (int r = 0; r < 4; ++r) { m[r] = -3.0e38f; lsum[r] = 0.f; }
#pragma unroll
    for (int nd = 0; nd < 4; ++nd) acc_o[nd] = (f32x4){0.f, 0.f, 0.f, 0.f};

    const int tend = q0 + 64;
    for (int t0 = 0; t0 < tend; t0 += KB) {
        __syncthreads();
#pragma unroll
        for (int it = 0; it < 2; ++it) {
            int g = it * 256 + tid;
            int t = g >> 3, dc = g & 7;
            *(u16x8*)&Ks[t][dc * 8] = *(const u16x8*)&kp[(size_t)(t0 + t) * (3 * CC) + dc * 8];
        }
#pragma unroll
        for (int it = 0; it < 2; ++it) {
            int g = it * 256 + tid;
            int t = g >> 3, dc = g & 7;
            u16x8 v = *(const u16x8*)&vp[(size_t)(t0 + t) * (3 * CC) + dc * 8];
#pragma unroll
            for (int e = 0; e < 8; ++e) Vs[dc * 8 + e][t] = v[e];
        }
        __syncthreads();

        f32x4 acc_s[4];
#pragma unroll
        for (int n = 0; n < 4; ++n) acc_s[n] = (f32x4){0.f, 0.f, 0.f, 0.f};
#pragma unroll
        for (int ks = 0; ks < 2; ++ks) {
#pragma unroll
            for (int n = 0; n < 4; ++n) {
                s16x8 kb = *(const s16x8*)&Ks[n * 16 + l15][ks * 32 + lq * 8];
                acc_s[n] = __builtin_amdgcn_mfma_f32_16x16x32_bf16(qf[ks], kb, acc_s[n], 0, 0, 0);
            }
        }

#pragma unroll
        for (int n = 0; n < 4; ++n) {
            int colg = t0 + n * 16 + l15;
#pragma unroll
            for (int r = 0; r < 4; ++r) {
                int rowg = q0 + wid * 16 + lq * 4 + r;
                float sv = acc_s[n][r] * 0.125f;
                acc_s[n][r] = (colg <= rowg) ? sv : -3.0e38f;
            }
        }
        float mt[4];
#pragma unroll
        for (int r = 0; r < 4; ++r)
            mt[r] = fmaxf(fmaxf(acc_s[0][r], acc_s[1][r]), fmaxf(acc_s[2][r], acc_s[3][r]));
#pragma unroll
        for (int off = 1; off < 16; off <<= 1)
#pragma unroll
            for (int r = 0; r < 4; ++r) mt[r] = fmaxf(mt[r], __shfl_xor(mt[r], off));

        float rs[4];
#pragma unroll
        for (int r = 0; r < 4; ++r) {
            float mn  = fmaxf(m[r], mt[r]);
            float scl = __expf(m[r] - mn);
            m[r] = mn;
            float ps = 0.f;
#pragma unroll
            for (int n = 0; n < 4; ++n) {
                float p = __expf(acc_s[n][r] - mn);
                acc_s[n][r] = p;
                ps += p;
            }
            rs[r] = ps;
            lsum[r] *= scl;
#pragma unroll
            for (int nd = 0; nd < 4; ++nd) acc_o[nd][r] *= scl;
        }
#pragma unroll
        for (int off = 1; off < 16; off <<= 1)
#pragma unroll
            for (int r = 0; r < 4; ++r) rs[r] += __shfl_xor(rs[r], off);
#pragma unroll
        for (int r = 0; r < 4; ++r) lsum[r] += rs[r];

#pragma unroll
        for (int n = 0; n < 4; ++n)
#pragma unroll
            for (int r = 0; r < 4; ++r)
                Ps[wid][lq * 4 + r][n * 16 + l15] = f2bf(acc_s[n][r]);
        __syncthreads();

#pragma unroll
        for (int ks = 0; ks < 2; ++ks) {
            s16x8 pa = *(const s16x8*)&Ps[wid][l15][ks * 32 + lq * 8];
#pragma unroll
            for (int nd = 0; nd < 4; ++nd) {
                s16x8 vb = *(const s16x8*)&Vs[nd * 16 + l15][ks * 32 + lq * 8];
                acc_o[nd] = __builtin_amdgcn_mfma_f32_16x16x32_bf16(pa, vb, acc_o[nd], 0, 0, 0);
            }
        }
    }

#pragma unroll
    for (int r = 0; r < 4; ++r) {
        float inv = 1.f / lsum[r];
        int rowg = q0 + wid * 16 + lq * 4 + r;
        u16* orow = o + ((size_t)b * SS + rowg) * CC + hh * DD;
#pragma unroll
        for (int nd = 0; nd < 4; ++nd)
            orow[nd * 16 + l15] = f2bf(acc_o[nd][r] * inv);
    }
}

// ---------------- loss (from lm_head partials) ----------------
__global__ __launch_bounds__(256) void lse_kernel(const float* __restrict__ partM,
                                                  const float* __restrict__ partS,
                                                  const float* __restrict__ logits,
                                                  const int* __restrict__ tgt,
                                                  float* __restrict__ lossp) {
    int row = blockIdx.x, tid = threadIdx.x;
    float m = -3.0e38f, s = 0.f;
    for (int i = tid; i < NBX; i += 256) {
        float pm = partM[(size_t)row * NBX + i];
        float ps = partS[(size_t)row * NBX + i];
        float nm = fmaxf(m, pm);
        s = s * __expf(m - nm) + ps * __expf(pm - nm);
        m = nm;
    }
#pragma unroll
    for (int off = 32; off; off >>= 1) {
        float om = __shfl_xor(m, off), os = __shfl_xor(s, off);
        float nm = fmaxf(m, om);
        s = s * __expf(m - nm) + os * __expf(om - nm);
        m = nm;
    }
    __shared__ float rm[4], rsh[4];
    int wid = tid >> 6;
    if ((tid & 63) == 0) { rm[wid] = m; rsh[wid] = s; }
    __syncthreads();
    if (tid == 0) {
        float M = fmaxf(fmaxf(rm[0], rm[1]), fmaxf(rm[2], rm[3]));
        float S = rsh[0] * __expf(rm[0] - M) + rsh[1] * __expf(rm[1] - M) +
                  rsh[2] * __expf(rm[2] - M) + rsh[3] * __expf(rm[3] - M);
        float lse = M + __logf(S);
        lossp[row] = lse - logits[(size_t)row * VV + tgt[row]];
    }
}

__global__ __launch_bounds__(256) void loss_reduce_kernel(const float* __restrict__ lossp,
                                                          float* __restrict__ out) {
    int tid = threadIdx.x;
    float s = 0.f;
    for (int i = tid; i < MM; i += 256) s += lossp[i];
#pragma unroll
    for (int off = 32; off; off >>= 1) s += __shfl_xor(s, off);
    __shared__ float r[4];
    if ((tid & 63) == 0) r[tid >> 6] = s;
    __syncthreads();
    if (tid == 0) out[0] = (r[0] + r[1] + r[2] + r[3]) * (1.0f / MM);
}

// ---------------- host ----------------
extern "C" void kernel_launch(void* const* d_in, const int* in_sizes, int n_in,
                              void* d_out, int out_size, void* d_ws, size_t ws_size,
                              hipStream_t stream) {
    const int*   idx     = (const int*)  d_in[0];
    const int*   targets = (const int*)  d_in[1];
    const float* wte     = (const float*)d_in[2];
    const float* wpe     = (const float*)d_in[3];
    const float* ln1w    = (const float*)d_in[4];
    const float* ln1b    = (const float*)d_in[5];
    const float* qkvw    = (const float*)d_in[6];
    const float* qkvbi   = (const float*)d_in[7];
    const float* projw   = (const float*)d_in[8];
    const float* projbi  = (const float*)d_in[9];
    const float* ln2w    = (const float*)d_in[10];
    const float* ln2b    = (const float*)d_in[11];
    const float* fcw     = (const float*)d_in[12];
    const float* fcbi    = (const float*)d_in[13];
    const float* fc2w    = (const float*)d_in[14];
    const float* fc2bi   = (const float*)d_in[15];
    const float* lnfw    = (const float*)d_in[16];
    const float* lnfb    = (const float*)d_in[17];
    float* logits = (float*)d_out;

    char* wsb = (char*)d_ws;
    size_t off = 0;
    auto alloc = [&](size_t n) -> char* {
        char* p = wsb + off;
        off = (off + n + 255) & ~(size_t)255;
        return p;
    };
    u16*   wteT  = (u16*)  alloc((size_t)VPAD * CC * 2);
    u16*   qkvT  = (u16*)  alloc((size_t)LNUM * 3 * CC * CC * 2);
    u16*   projT = (u16*)  alloc((size_t)LNUM * CC * CC * 2);
    u16*   fcT   = (u16*)  alloc((size_t)LNUM * FFD * CC * 2);
    u16*   fc2T  = (u16*)  alloc((size_t)LNUM * CC * FFD * 2);
    float* h     = (float*)alloc((size_t)MM * CC * 4);
    u16*   xb    = (u16*)  alloc((size_t)MM * CC * 2);
    u16*   qkvb  = (u16*)  alloc((size_t)MM * 3 * CC * 2);
    u16*   ob    = (u16*)  alloc((size_t)MM * CC * 2);
    u16*   gb    = (u16*)  alloc((size_t)MM * FFD * 2);
    float* lossp = (float*)alloc((size_t)MM * 4);
    float* partM = (float*)alloc((size_t)MM * NBX * 4);
    float* partS = (float*)alloc((size_t)MM * NBX * 4);

    // weight prep
    {
        int blocks = (int)(((size_t)VPAD * CC / 4 + 255) / 256);
        wte_conv_kernel<<<blocks, 256, 0, stream>>>(wte, wteT);
    }
    transpose_conv_kernel<<<dim3(3 * CC / 32, CC / 32, LNUM), dim3(32, 8), 0, stream>>>(qkvw, qkvT, CC, 3 * CC);
    transpose_conv_kernel<<<dim3(CC / 32, CC / 32, LNUM),     dim3(32, 8), 0, stream>>>(projw, projT, CC, CC);
    transpose_conv_kernel<<<dim3(FFD / 32, CC / 32, LNUM),    dim3(32, 8), 0, stream>>>(fcw, fcT, CC, FFD);
    transpose_conv_kernel<<<dim3(CC / 32, FFD / 32, LNUM),    dim3(32, 8), 0, stream>>>(fc2w, fc2T, FFD, CC);

    embed_kernel<<<MM, 256, 0, stream>>>(idx, wte, wpe, h);

    for (int l = 0; l < LNUM; ++l) {
        const u16* qkvT_l  = qkvT  + (size_t)l * 3 * CC * CC;
        const u16* projT_l = projT + (size_t)l * CC * CC;
        const u16* fcT_l   = fcT   + (size_t)l * FFD * CC;
        const u16* fc2T_l  = fc2T  + (size_t)l * CC * FFD;

        ln_kernel<<<MM, 256, 0, stream>>>(h, ln1w + (size_t)l * CC, ln1b + (size_t)l * CC, xb);
        gemm_bt_kernel<128, 128, 0><<<dim3(3 * CC / 128, MM / 128), 256, 0, stream>>>(
            xb, qkvT_l, qkvbi + (size_t)l * 3 * CC, nullptr, qkvb, CC, 3 * CC, nullptr, nullptr);
        attn_mfma_kernel<<<BB * HH * (SS / 64), 256, 0, stream>>>(qkvb, ob);
        gemm_bt_kernel<64, 64, 2><<<dim3(CC / 64, MM / 64), 256, 0, stream>>>(
            ob, projT_l, projbi + (size_t)l * CC, h, nullptr, CC, CC, nullptr, nullptr);
        ln_kernel<<<MM, 256, 0, stream>>>(h, ln2w + (size_t)l * CC, ln2b + (size_t)l * CC, xb);
        gemm_bt_kernel<128, 128, 1><<<dim3(FFD / 128, MM / 128), 256, 0, stream>>>(
            xb, fcT_l, fcbi + (size_t)l * FFD, nullptr, gb, CC, FFD, nullptr, nullptr);
        gemm_bt_kernel<64, 64, 2><<<dim3(CC / 64, MM / 64), 256, 0, stream>>>(
            gb, fc2T_l, fc2bi + (size_t)l * CC, h, nullptr, FFD, CC, nullptr, nullptr);
    }

    ln_kernel<<<MM, 256, 0, stream>>>(h, lnfw, lnfb, xb);
    gemm_bt_kernel<128, 128, 3><<<dim3(VPAD / 128, MM / 128), 256, 0, stream>>>(
        xb, wteT, nullptr, logits, nullptr, CC, VV, partM, partS);

    lse_kernel<<<MM, 256, 0, stream>>>(partM, partS, logits, targets, lossp);
    loss_reduce_kernel<<<1, 256, 0, stream>>>(lossp, logits + (size_t)MM * VV);
}

// Round 5
// 2284.663 us; speedup vs baseline: 2.9509x; 1.0406x over previous
//
#include <hip/hip_runtime.h>
#include <hip/hip_bf16.h>
#include <cstdint>
#include <cstddef>

// ---- model dims ----
constexpr int LNUM = 12;
constexpr int BB   = 2;
constexpr int SS   = 1024;
constexpr int CC   = 768;
constexpr int HH   = 12;
constexpr int DD   = 64;      // C/H
constexpr int FFD  = 3072;    // 4C
constexpr int VV   = 50257;
constexpr int VPAD = 50304;   // V rounded up to 128
constexpr int MM   = BB * SS; // 2048 token rows
constexpr int NBX  = VPAD / 128; // lm_head col-blocks = 393

typedef unsigned short u16;
typedef short     s16x8 __attribute__((ext_vector_type(8)));
typedef float     f32x4 __attribute__((ext_vector_type(4)));
typedef u16       u16x4 __attribute__((ext_vector_type(4)));
typedef u16       u16x8 __attribute__((ext_vector_type(8)));

__device__ __forceinline__ float bf2f(u16 v) {
    return __uint_as_float(((unsigned)v) << 16);
}
__device__ __forceinline__ u16 f2bf(float f) {
    unsigned u = __float_as_uint(f);
    return (u16)((u + 0x7fffu + ((u >> 16) & 1u)) >> 16);
}

// ---------------- weight prep ----------------

// wte [V][C] f32 -> bf16 [VPAD][C], pad rows zero
__global__ __launch_bounds__(256) void wte_conv_kernel(const float* __restrict__ wte,
                                                       u16* __restrict__ out) {
    size_t i4 = ((size_t)blockIdx.x * 256 + threadIdx.x) * 4;
    if (i4 >= (size_t)VPAD * CC) return;
    size_t r = i4 / CC;
    u16x4 o;
    if (r < (size_t)VV) {
        const float4 v = *(const float4*)&wte[i4];
        o[0] = f2bf(v.x); o[1] = f2bf(v.y); o[2] = f2bf(v.z); o[3] = f2bf(v.w);
    } else {
        o[0] = o[1] = o[2] = o[3] = 0;
    }
    *(u16x4*)&out[i4] = o;
}

// in: [L][R][Cn] f32   out: [L][Cn][R] bf16   (R,Cn multiples of 32)
__global__ __launch_bounds__(256) void transpose_conv_kernel(const float* __restrict__ in,
                                                             u16* __restrict__ out,
                                                             int R, int Cn) {
    __shared__ float tile[32][33];
    const float* inp = in + (size_t)blockIdx.z * R * Cn;
    u16* outp = out + (size_t)blockIdx.z * R * Cn;
    int c  = blockIdx.x * 32 + threadIdx.x;
    int r0 = blockIdx.y * 32;
#pragma unroll
    for (int i = 0; i < 4; ++i) {
        int r = r0 + threadIdx.y + i * 8;
        tile[threadIdx.y + i * 8][threadIdx.x] = inp[(size_t)r * Cn + c];
    }
    __syncthreads();
    int oc = r0 + threadIdx.x; // output col = input row (k)
#pragma unroll
    for (int i = 0; i < 4; ++i) {
        int orow = blockIdx.x * 32 + threadIdx.y + i * 8; // output row (n)
        outp[(size_t)orow * R + oc] = f2bf(tile[threadIdx.x][threadIdx.y + i * 8]);
    }
}

// ---------------- embedding ----------------
__global__ __launch_bounds__(256) void embed_kernel(const int* __restrict__ idx,
                                                    const float* __restrict__ wte,
                                                    const float* __restrict__ wpe,
                                                    float* __restrict__ h) {
    int row = blockIdx.x;          // 0..2047
    int s   = row & (SS - 1);
    int tok = idx[row];
    const float* we = wte + (size_t)tok * CC;
    const float* pe = wpe + (size_t)s * CC;
    float* hr = h + (size_t)row * CC;
    for (int c = threadIdx.x; c < CC; c += 256) hr[c] = we[c] + pe[c];
}

// ---------------- layernorm: f32 in -> bf16 out ----------------
__global__ __launch_bounds__(256) void ln_kernel(const float* __restrict__ h,
                                                 const float* __restrict__ w,
                                                 const float* __restrict__ b,
                                                 u16* __restrict__ x) {
    int row = blockIdx.x, tid = threadIdx.x;
    const float* hr = h + (size_t)row * CC;
    float v0 = hr[tid], v1 = hr[tid + 256], v2 = hr[tid + 512];
    float s  = v0 + v1 + v2;
    float s2 = v0 * v0 + v1 * v1 + v2 * v2;
#pragma unroll
    for (int off = 32; off; off >>= 1) {
        s  += __shfl_xor(s, off);
        s2 += __shfl_xor(s2, off);
    }
    __shared__ float rs[4], rs2[4], stat[2];
    int wid = tid >> 6;
    if ((tid & 63) == 0) { rs[wid] = s; rs2[wid] = s2; }
    __syncthreads();
    if (tid == 0) {
        float ts  = rs[0] + rs[1] + rs[2] + rs[3];
        float ts2 = rs2[0] + rs2[1] + rs2[2] + rs2[3];
        float mean = ts * (1.0f / CC);
        float var  = ts2 * (1.0f / CC) - mean * mean;
        stat[0] = mean;
        stat[1] = rsqrtf(var + 1e-5f);
    }
    __syncthreads();
    float mean = stat[0], rstd = stat[1];
    size_t base = (size_t)row * CC;
    x[base + tid]       = f2bf((v0 - mean) * rstd * w[tid]       + b[tid]);
    x[base + tid + 256] = f2bf((v1 - mean) * rstd * w[tid + 256] + b[tid + 256]);
    x[base + tid + 512] = f2bf((v2 - mean) * rstd * w[tid + 512] + b[tid + 512]);
}

// ---------------- GEMM: C[M,N] = A[M,K] @ Bt[N,K]^T  (bf16 in, f32 acc) ----------------
// Reg-staged (global->VGPR->LDS), single 32KB LDS buffer, 2-barrier loop,
// T14 async split: next tile's global loads issue before compute so HBM/L2
// latency hides under MFMA. LDS XOR chunk-swizzle, both-sides (rule #21):
// thread staging physical chunk (r, p) loads GLOBAL logical chunk p^(r&7);
// ds_write linear; ds_read XORs the chunk index (proven 0-conflict in r4).
// XCD-chunked bijective remap, column-major work ids (B-panel L2 reuse).
// EPI: 0 = bias -> bf16 out        (qkv)
//      1 = bias+gelu -> bf16 out   (fc)
//      2 = bias, residual add into f32 outf (proj, fc2)
//      3 = no bias, f32 logits out (col<VV) + per-block lse partials (lm_head)
template <int BM, int BN, int EPI>
__global__ __launch_bounds__(256)
void gemm_bt_kernel(const u16* __restrict__ A, const u16* __restrict__ Bt,
                    const float* __restrict__ bias, float* __restrict__ outf,
                    u16* __restrict__ outb, int K, long long ldo,
                    float* __restrict__ partM, float* __restrict__ partS) {
    constexpr int MR  = BM / 32, NR = BN / 32;   // fragment repeats per wave
    constexpr int ACH = BM * 64 / (256 * 8);     // staged A chunks per thread
    constexpr int BCH = BN * 64 / (256 * 8);
    __shared__ u16 As[BM * 64];
    __shared__ u16 Bs[BN * 64];
    const int tid  = threadIdx.x;
    const int lane = tid & 63;
    const int wid  = tid >> 6;
    const int l15  = lane & 15;
    const int lq   = lane >> 4;
    const int wm   = wid & 1;
    const int wn   = wid >> 1;
    const int rx   = l15 & 7;                    // read-side XOR chunk term

    // XCD-chunked bijective remap; work id is column-major (bx outer, by inner)
    const int gx = gridDim.x, gy = gridDim.y;
    const int nwg = gx * gy;
    const int pos = blockIdx.y * gx + blockIdx.x;      // dispatch order
    const int qc  = nwg >> 3, rc = nwg & 7;
    const int xcd = pos & 7, cidx = pos >> 3;
    const int wgid = (xcd < rc ? xcd * (qc + 1) : rc * (qc + 1) + (xcd - rc) * qc) + cidx;
    const int bx = wgid / gy, by = wgid % gy;
    const int bm0 = by * BM, bn0 = bx * BN;

    f32x4 acc[MR][NR];
#pragma unroll
    for (int m = 0; m < MR; ++m)
#pragma unroll
        for (int n = 0; n < NR; ++n) acc[m][n] = (f32x4){0.f, 0.f, 0.f, 0.f};

    u16x8 areg[ACH], breg[BCH];
    // thread's staged chunk g = it*256+tid: LDS row r=g>>3, physical chunk g&7,
    // global logical chunk (g&7)^(r&7)
    auto ldreg = [&](int kt) {
#pragma unroll
        for (int it = 0; it < ACH; ++it) {
            int g = it * 256 + tid, r = g >> 3, c = ((g & 7) ^ (r & 7)) * 8;
            areg[it] = *(const u16x8*)&A[(size_t)(bm0 + r) * (size_t)K + kt + c];
        }
#pragma unroll
        for (int it = 0; it < BCH; ++it) {
            int g = it * 256 + tid, r = g >> 3, c = ((g & 7) ^ (r & 7)) * 8;
            breg[it] = *(const u16x8*)&Bt[(size_t)(bn0 + r) * (size_t)K + kt + c];
        }
    };
    auto wlds = [&]() {
#pragma unroll
        for (int it = 0; it < ACH; ++it) *(u16x8*)&As[(it * 256 + tid) * 8] = areg[it];
#pragma unroll
        for (int it = 0; it < BCH; ++it) *(u16x8*)&Bs[(it * 256 + tid) * 8] = breg[it];
    };
    auto compute = [&]() {
#pragma unroll
        for (int ks = 0; ks < 2; ++ks) {
            s16x8 af[MR], bfr[NR];
#pragma unroll
            for (int m = 0; m < MR; ++m) {
                int row = wm * (BM / 2) + m * 16 + l15;
                af[m] = *(const s16x8*)&As[row * 64 + (((ks * 4 + lq) ^ rx) * 8)];
            }
#pragma unroll
            for (int n = 0; n < NR; ++n) {
                int row = wn * (BN / 2) + n * 16 + l15;
                bfr[n] = *(const s16x8*)&Bs[row * 64 + (((ks * 4 + lq) ^ rx) * 8)];
            }
#pragma unroll
            for (int m = 0; m < MR; ++m)
#pragma unroll
                for (int n = 0; n < NR; ++n)
                    acc[m][n] = __builtin_amdgcn_mfma_f32_16x16x32_bf16(af[m], bfr[n], acc[m][n], 0, 0, 0);
        }
    };

    const int nk = K >> 6;
    ldreg(0);
    for (int t = 0; t < nk; ++t) {
        __syncthreads();          // previous compute done; LDS free
        wlds();
        __syncthreads();          // tile visible to all waves
        if (t + 1 < nk) ldreg((t + 1) << 6);  // issue next loads under compute
        compute();
    }

    // epilogue: C/D layout col=lane&15, row=4*(lane>>4)+reg
#pragma unroll
    for (int m = 0; m < MR; ++m) {
#pragma unroll
        for (int n = 0; n < NR; ++n) {
#pragma unroll
            for (int r = 0; r < 4; ++r) {
                int row = bm0 + wm * (BM / 2) + m * 16 + lq * 4 + r;
                int col = bn0 + wn * (BN / 2) + n * 16 + l15;
                float v = acc[m][n][r];
                if (EPI != 3) v += bias[col];
                if (EPI == 1) {
                    float xg = v;
                    v = 0.5f * xg * (1.0f + tanhf(0.7978845608028654f * (xg + 0.044715f * xg * xg * xg)));
                }
                if (EPI == 0 || EPI == 1) {
                    outb[(size_t)row * ldo + col] = f2bf(v);
                } else if (EPI == 2) {
                    outf[(size_t)row * ldo + col] += v;
                } else {
                    if (col < VV) outf[(size_t)row * ldo + col] = v;
                }
            }
        }
    }

    // lm_head: per-row partial logsumexp over this block's BN cols
    if constexpr (EPI == 3) {
        __shared__ float redM[2][BM], redS[2][BM];
#pragma unroll
        for (int m = 0; m < MR; ++m) {
#pragma unroll
            for (int r = 0; r < 4; ++r) {
                float mx = -3.0e38f;
#pragma unroll
                for (int n = 0; n < NR; ++n) {
                    int colg = bn0 + wn * (BN / 2) + n * 16 + l15;
                    float v = (colg < VV) ? acc[m][n][r] : -3.0e38f;
                    mx = fmaxf(mx, v);
                }
#pragma unroll
                for (int off = 1; off < 16; off <<= 1) mx = fmaxf(mx, __shfl_xor(mx, off));
                float sm = 0.f;
#pragma unroll
                for (int n = 0; n < NR; ++n) {
                    int colg = bn0 + wn * (BN / 2) + n * 16 + l15;
                    if (colg < VV) sm += __expf(acc[m][n][r] - mx);
                }
#pragma unroll
                for (int off = 1; off < 16; off <<= 1) sm += __shfl_xor(sm, off);
                if (l15 == 0) {
                    int rl = wm * (BM / 2) + m * 16 + lq * 4 + r;
                    redM[wn][rl] = mx;
                    redS[wn][rl] = sm;
                }
            }
        }
        __syncthreads();
        if (tid < BM) {
            float m0 = redM[0][tid], m1 = redM[1][tid];
            float M = fmaxf(m0, m1);
            float S = redS[0][tid] * __expf(m0 - M) + redS[1][tid] * __expf(m1 - M);
            size_t rowg = (size_t)(bm0 + tid);
            partM[rowg * NBX + bx] = M;
            partS[rowg * NBX + bx] = S;
        }
    }
}

// ---------------- MFMA flash attention ----------------
// One block = 64 query rows of one (b,h); 4 waves, each owns 16 rows.
__global__ __launch_bounds__(256) void attn_mfma_kernel(const u16* __restrict__ qkv,
                                                        u16* __restrict__ o) {
    constexpr int KB = 64, PADC = 72;
    __shared__ u16 Ks[KB][PADC];     // K[t][d]
    __shared__ u16 Vs[DD][PADC];     // V^T[d][t]
    __shared__ u16 Ps[4][16][PADC];  // per-wave P tile [row][t]

    const int tid = threadIdx.x, lane = tid & 63, wid = tid >> 6;
    const int l15 = lane & 15, lq = lane >> 4;
    const int blk = blockIdx.x;
    const int q0  = (blk & (SS / 64 - 1)) * 64;
    const int bh  = blk / (SS / 64);
    const int b   = bh / HH, hh = bh % HH;

    const size_t base = (size_t)b * SS * (3 * CC);
    const u16* qp = qkv + base + hh * DD;            // row stride 3C
    const u16* kp = qkv + base + CC + hh * DD;
    const u16* vp = qkv + base + 2 * CC + hh * DD;

    s16x8 qf[2];
    {
        const u16* qr = qp + (size_t)(q0 + wid * 16 + l15) * (3 * CC);
        qf[0] = *(const s16x8*)&qr[lq * 8];
        qf[1] = *(const s16x8*)&qr[32 + lq * 8];
    }

    float m[4], lsum[4];
    f32x4 acc_o[4];
#pragma unroll
    for (int r = 0; r < 4; ++r) { m[r] = -3.0e38f; lsum[r] = 0.f; }
#pragma unroll
    for (int nd = 0; nd < 4; ++nd) acc_o[nd] = (f32x4){0.f, 0.f, 0.f, 0.f};

    const int tend = q0 + 64;
    for (int t0 = 0; t0 < tend; t0 += KB) {
        __syncthreads();
#pragma unroll
        for (int it = 0; it < 2; ++it) {
            int g = it * 256 + tid;
            int t = g >> 3, dc = g & 7;
            *(u16x8*)&Ks[t][dc * 8] = *(const u16x8*)&kp[(size_t)(t0 + t) * (3 * CC) + dc * 8];
        }
#pragma unroll
        for (int it = 0; it < 2; ++it) {
            int g = it * 256 + tid;
            int t = g >> 3, dc = g & 7;
            u16x8 v = *(const u16x8*)&vp[(size_t)(t0 + t) * (3 * CC) + dc * 8];
#pragma unroll
            for (int e = 0; e < 8; ++e) Vs[dc * 8 + e][t] = v[e];
        }
        __syncthreads();

        f32x4 acc_s[4];
#pragma unroll
        for (int n = 0; n < 4; ++n) acc_s[n] = (f32x4){0.f, 0.f, 0.f, 0.f};
#pragma unroll
        for (int ks = 0; ks < 2; ++ks) {
#pragma unroll
            for (int n = 0; n < 4; ++n) {
                s16x8 kb = *(const s16x8*)&Ks[n * 16 + l15][ks * 32 + lq * 8];
                acc_s[n] = __builtin_amdgcn_mfma_f32_16x16x32_bf16(qf[ks], kb, acc_s[n], 0, 0, 0);
            }
        }

#pragma unroll
        for (int n = 0; n < 4; ++n) {
            int colg = t0 + n * 16 + l15;
#pragma unroll
            for (int r = 0; r < 4; ++r) {
                int rowg = q0 + wid * 16 + lq * 4 + r;
                float sv = acc_s[n][r] * 0.125f;
                acc_s[n][r] = (colg <= rowg) ? sv : -3.0e38f;
            }
        }
        float mt[4];
#pragma unroll
        for (int r = 0; r < 4; ++r)
            mt[r] = fmaxf(fmaxf(acc_s[0][r], acc_s[1][r]), fmaxf(acc_s[2][r], acc_s[3][r]));
#pragma unroll
        for (int off = 1; off < 16; off <<= 1)
#pragma unroll
            for (int r = 0; r < 4; ++r) mt[r] = fmaxf(mt[r], __shfl_xor(mt[r], off));

        float rs[4];
#pragma unroll
        for (int r = 0; r < 4; ++r) {
            float mn  = fmaxf(m[r], mt[r]);
            float scl = __expf(m[r] - mn);
            m[r] = mn;
            float ps = 0.f;
#pragma unroll
            for (int n = 0; n < 4; ++n) {
                float p = __expf(acc_s[n][r] - mn);
                acc_s[n][r] = p;
                ps += p;
            }
            rs[r] = ps;
            lsum[r] *= scl;
#pragma unroll
            for (int nd = 0; nd < 4; ++nd) acc_o[nd][r] *= scl;
        }
#pragma unroll
        for (int off = 1; off < 16; off <<= 1)
#pragma unroll
            for (int r = 0; r < 4; ++r) rs[r] += __shfl_xor(rs[r], off);
#pragma unroll
        for (int r = 0; r < 4; ++r) lsum[r] += rs[r];

#pragma unroll
        for (int n = 0; n < 4; ++n)
#pragma unroll
            for (int r = 0; r < 4; ++r)
                Ps[wid][lq * 4 + r][n * 16 + l15] = f2bf(acc_s[n][r]);
        __syncthreads();

#pragma unroll
        for (int ks = 0; ks < 2; ++ks) {
            s16x8 pa = *(const s16x8*)&Ps[wid][l15][ks * 32 + lq * 8];
#pragma unroll
            for (int nd = 0; nd < 4; ++nd) {
                s16x8 vb = *(const s16x8*)&Vs[nd * 16 + l15][ks * 32 + lq * 8];
                acc_o[nd] = __builtin_amdgcn_mfma_f32_16x16x32_bf16(pa, vb, acc_o[nd], 0, 0, 0);
            }
        }
    }

#pragma unroll
    for (int r = 0; r < 4; ++r) {
        float inv = 1.f / lsum[r];
        int rowg = q0 + wid * 16 + lq * 4 + r;
        u16* orow = o + ((size_t)b * SS + rowg) * CC + hh * DD;
#pragma unroll
        for (int nd = 0; nd < 4; ++nd)
            orow[nd * 16 + l15] = f2bf(acc_o[nd][r] * inv);
    }
}

// ---------------- loss (from lm_head partials) ----------------
__global__ __launch_bounds__(256) void lse_kernel(const float* __restrict__ partM,
                                                  const float* __restrict__ partS,
                                                  const float* __restrict__ logits,
                                                  const int* __restrict__ tgt,
                                                  float* __restrict__ lossp) {
    int row = blockIdx.x, tid = threadIdx.x;
    float m = -3.0e38f, s = 0.f;
    for (int i = tid; i < NBX; i += 256) {
        float pm = partM[(size_t)row * NBX + i];
        float ps = partS[(size_t)row * NBX + i];
        float nm = fmaxf(m, pm);
        s = s * __expf(m - nm) + ps * __expf(pm - nm);
        m = nm;
    }
#pragma unroll
    for (int off = 32; off; off >>= 1) {
        float om = __shfl_xor(m, off), os = __shfl_xor(s, off);
        float nm = fmaxf(m, om);
        s = s * __expf(m - nm) + os * __expf(om - nm);
        m = nm;
    }
    __shared__ float rm[4], rsh[4];
    int wid = tid >> 6;
    if ((tid & 63) == 0) { rm[wid] = m; rsh[wid] = s; }
    __syncthreads();
    if (tid == 0) {
        float M = fmaxf(fmaxf(rm[0], rm[1]), fmaxf(rm[2], rm[3]));
        float S = rsh[0] * __expf(rm[0] - M) + rsh[1] * __expf(rm[1] - M) +
                  rsh[2] * __expf(rm[2] - M) + rsh[3] * __expf(rm[3] - M);
        float lse = M + __logf(S);
        lossp[row] = lse - logits[(size_t)row * VV + tgt[row]];
    }
}

__global__ __launch_bounds__(256) void loss_reduce_kernel(const float* __restrict__ lossp,
                                                          float* __restrict__ out) {
    int tid = threadIdx.x;
    float s = 0.f;
    for (int i = tid; i < MM; i += 256) s += lossp[i];
#pragma unroll
    for (int off = 32; off; off >>= 1) s += __shfl_xor(s, off);
    __shared__ float r[4];
    if ((tid & 63) == 0) r[tid >> 6] = s;
    __syncthreads();
    if (tid == 0) out[0] = (r[0] + r[1] + r[2] + r[3]) * (1.0f / MM);
}

// ---------------- host ----------------
extern "C" void kernel_launch(void* const* d_in, const int* in_sizes, int n_in,
                              void* d_out, int out_size, void* d_ws, size_t ws_size,
                              hipStream_t stream) {
    const int*   idx     = (const int*)  d_in[0];
    const int*   targets = (const int*)  d_in[1];
    const float* wte     = (const float*)d_in[2];
    const float* wpe     = (const float*)d_in[3];
    const float* ln1w    = (const float*)d_in[4];
    const float* ln1b    = (const float*)d_in[5];
    const float* qkvw    = (const float*)d_in[6];
    const float* qkvbi   = (const float*)d_in[7];
    const float* projw   = (const float*)d_in[8];
    const float* projbi  = (const float*)d_in[9];
    const float* ln2w    = (const float*)d_in[10];
    const float* ln2b    = (const float*)d_in[11];
    const float* fcw     = (const float*)d_in[12];
    const float* fcbi    = (const float*)d_in[13];
    const float* fc2w    = (const float*)d_in[14];
    const float* fc2bi   = (const float*)d_in[15];
    const float* lnfw    = (const float*)d_in[16];
    const float* lnfb    = (const float*)d_in[17];
    float* logits = (float*)d_out;

    char* wsb = (char*)d_ws;
    size_t off = 0;
    auto alloc = [&](size_t n) -> char* {
        char* p = wsb + off;
        off = (off + n + 255) & ~(size_t)255;
        return p;
    };
    u16*   wteT  = (u16*)  alloc((size_t)VPAD * CC * 2);
    u16*   qkvT  = (u16*)  alloc((size_t)LNUM * 3 * CC * CC * 2);
    u16*   projT = (u16*)  alloc((size_t)LNUM * CC * CC * 2);
    u16*   fcT   = (u16*)  alloc((size_t)LNUM * FFD * CC * 2);
    u16*   fc2T  = (u16*)  alloc((size_t)LNUM * CC * FFD * 2);
    float* h     = (float*)alloc((size_t)MM * CC * 4);
    u16*   xb    = (u16*)  alloc((size_t)MM * CC * 2);
    u16*   qkvb  = (u16*)  alloc((size_t)MM * 3 * CC * 2);
    u16*   ob    = (u16*)  alloc((size_t)MM * CC * 2);
    u16*   gb    = (u16*)  alloc((size_t)MM * FFD * 2);
    float* lossp = (float*)alloc((size_t)MM * 4);
    float* partM = (float*)alloc((size_t)MM * NBX * 4);
    float* partS = (float*)alloc((size_t)MM * NBX * 4);

    // weight prep
    {
        int blocks = (int)(((size_t)VPAD * CC / 4 + 255) / 256);
        wte_conv_kernel<<<blocks, 256, 0, stream>>>(wte, wteT);
    }
    transpose_conv_kernel<<<dim3(3 * CC / 32, CC / 32, LNUM), dim3(32, 8), 0, stream>>>(qkvw, qkvT, CC, 3 * CC);
    transpose_conv_kernel<<<dim3(CC / 32, CC / 32, LNUM),     dim3(32, 8), 0, stream>>>(projw, projT, CC, CC);
    transpose_conv_kernel<<<dim3(FFD / 32, CC / 32, LNUM),    dim3(32, 8), 0, stream>>>(fcw, fcT, CC, FFD);
    transpose_conv_kernel<<<dim3(CC / 32, FFD / 32, LNUM),    dim3(32, 8), 0, stream>>>(fc2w, fc2T, FFD, CC);

    embed_kernel<<<MM, 256, 0, stream>>>(idx, wte, wpe, h);

    for (int l = 0; l < LNUM; ++l) {
        const u16* qkvT_l  = qkvT  + (size_t)l * 3 * CC * CC;
        const u16* projT_l = projT + (size_t)l * CC * CC;
        const u16* fcT_l   = fcT   + (size_t)l * FFD * CC;
        const u16* fc2T_l  = fc2T  + (size_t)l * CC * FFD;

        ln_kernel<<<MM, 256, 0, stream>>>(h, ln1w + (size_t)l * CC, ln1b + (size_t)l * CC, xb);
        gemm_bt_kernel<128, 128, 0><<<dim3(3 * CC / 128, MM / 128), 256, 0, stream>>>(
            xb, qkvT_l, qkvbi + (size_t)l * 3 * CC, nullptr, qkvb, CC, 3 * CC, nullptr, nullptr);
        attn_mfma_kernel<<<BB * HH * (SS / 64), 256, 0, stream>>>(qkvb, ob);
        gemm_bt_kernel<64, 64, 2><<<dim3(CC / 64, MM / 64), 256, 0, stream>>>(
            ob, projT_l, projbi + (size_t)l * CC, h, nullptr, CC, CC, nullptr, nullptr);
        ln_kernel<<<MM, 256, 0, stream>>>(h, ln2w + (size_t)l * CC, ln2b + (size_t)l * CC, xb);
        gemm_bt_kernel<128, 128, 1><<<dim3(FFD / 128, MM / 128), 256, 0, stream>>>(
            xb, fcT_l, fcbi + (size_t)l * FFD, nullptr, gb, CC, FFD, nullptr, nullptr);
        gemm_bt_kernel<64, 64, 2><<<dim3(CC / 64, MM / 64), 256, 0, stream>>>(
            gb, fc2T_l, fc2bi + (size_t)l * CC, h, nullptr, FFD, CC, nullptr, nullptr);
    }

    ln_kernel<<<MM, 256, 0, stream>>>(h, lnfw, lnfb, xb);
    gemm_bt_kernel<128, 128, 3><<<dim3(VPAD / 128, MM / 128), 256, 0, stream>>>(
        xb, wteT, nullptr, logits, nullptr, CC, VV, partM, partS);

    lse_kernel<<<MM, 256, 0, stream>>>(partM, partS, logits, targets, lossp);
    loss_reduce_kernel<<<1, 256, 0, stream>>>(lossp, logits + (size_t)MM * VV);
}

// Round 6
// 2084.770 us; speedup vs baseline: 3.2338x; 1.0959x over previous
//
#include <hip/hip_runtime.h>
#include <hip/hip_bf16.h>
#include <cstdint>
#include <cstddef>

// ---- model dims ----
constexpr int LNUM = 12;
constexpr int BB   = 2;
constexpr int SS   = 1024;
constexpr int CC   = 768;
constexpr int HH   = 12;
constexpr int DD   = 64;      // C/H
constexpr int FFD  = 3072;    // 4C
constexpr int VV   = 50257;
constexpr int VPAD = 50304;   // V rounded up to 128
constexpr int MM   = BB * SS; // 2048 token rows
constexpr int NBX  = VPAD / 128; // lm_head col-blocks = 393

typedef unsigned short u16;
typedef short     s16x8 __attribute__((ext_vector_type(8)));
typedef float     f32x4 __attribute__((ext_vector_type(4)));
typedef u16       u16x4 __attribute__((ext_vector_type(4)));
typedef u16       u16x8 __attribute__((ext_vector_type(8)));

__device__ __forceinline__ float bf2f(u16 v) {
    return __uint_as_float(((unsigned)v) << 16);
}
__device__ __forceinline__ u16 f2bf(float f) {
    unsigned u = __float_as_uint(f);
    return (u16)((u + 0x7fffu + ((u >> 16) & 1u)) >> 16);
}

// ---------------- weight prep ----------------

// wte [V][C] f32 -> bf16 [VPAD][C], pad rows zero
__global__ __launch_bounds__(256) void wte_conv_kernel(const float* __restrict__ wte,
                                                       u16* __restrict__ out) {
    size_t i4 = ((size_t)blockIdx.x * 256 + threadIdx.x) * 4;
    if (i4 >= (size_t)VPAD * CC) return;
    size_t r = i4 / CC;
    u16x4 o;
    if (r < (size_t)VV) {
        const float4 v = *(const float4*)&wte[i4];
        o[0] = f2bf(v.x); o[1] = f2bf(v.y); o[2] = f2bf(v.z); o[3] = f2bf(v.w);
    } else {
        o[0] = o[1] = o[2] = o[3] = 0;
    }
    *(u16x4*)&out[i4] = o;
}

// in: [L][R][Cn] f32   out: [L][Cn][R] bf16   (R,Cn multiples of 32)
__global__ __launch_bounds__(256) void transpose_conv_kernel(const float* __restrict__ in,
                                                             u16* __restrict__ out,
                                                             int R, int Cn) {
    __shared__ float tile[32][33];
    const float* inp = in + (size_t)blockIdx.z * R * Cn;
    u16* outp = out + (size_t)blockIdx.z * R * Cn;
    int c  = blockIdx.x * 32 + threadIdx.x;
    int r0 = blockIdx.y * 32;
#pragma unroll
    for (int i = 0; i < 4; ++i) {
        int r = r0 + threadIdx.y + i * 8;
        tile[threadIdx.y + i * 8][threadIdx.x] = inp[(size_t)r * Cn + c];
    }
    __syncthreads();
    int oc = r0 + threadIdx.x; // output col = input row (k)
#pragma unroll
    for (int i = 0; i < 4; ++i) {
        int orow = blockIdx.x * 32 + threadIdx.y + i * 8; // output row (n)
        outp[(size_t)orow * R + oc] = f2bf(tile[threadIdx.x][threadIdx.y + i * 8]);
    }
}

// ---------------- embedding ----------------
__global__ __launch_bounds__(256) void embed_kernel(const int* __restrict__ idx,
                                                    const float* __restrict__ wte,
                                                    const float* __restrict__ wpe,
                                                    float* __restrict__ h) {
    int row = blockIdx.x;          // 0..2047
    int s   = row & (SS - 1);
    int tok = idx[row];
    const float* we = wte + (size_t)tok * CC;
    const float* pe = wpe + (size_t)s * CC;
    float* hr = h + (size_t)row * CC;
    for (int c = threadIdx.x; c < CC; c += 256) hr[c] = we[c] + pe[c];
}

// ---------------- layernorm: f32 in -> bf16 out ----------------
__global__ __launch_bounds__(256) void ln_kernel(const float* __restrict__ h,
                                                 const float* __restrict__ w,
                                                 const float* __restrict__ b,
                                                 u16* __restrict__ x) {
    int row = blockIdx.x, tid = threadIdx.x;
    const float* hr = h + (size_t)row * CC;
    float v0 = hr[tid], v1 = hr[tid + 256], v2 = hr[tid + 512];
    float s  = v0 + v1 + v2;
    float s2 = v0 * v0 + v1 * v1 + v2 * v2;
#pragma unroll
    for (int off = 32; off; off >>= 1) {
        s  += __shfl_xor(s, off);
        s2 += __shfl_xor(s2, off);
    }
    __shared__ float rs[4], rs2[4], stat[2];
    int wid = tid >> 6;
    if ((tid & 63) == 0) { rs[wid] = s; rs2[wid] = s2; }
    __syncthreads();
    if (tid == 0) {
        float ts  = rs[0] + rs[1] + rs[2] + rs[3];
        float ts2 = rs2[0] + rs2[1] + rs2[2] + rs2[3];
        float mean = ts * (1.0f / CC);
        float var  = ts2 * (1.0f / CC) - mean * mean;
        stat[0] = mean;
        stat[1] = rsqrtf(var + 1e-5f);
    }
    __syncthreads();
    float mean = stat[0], rstd = stat[1];
    size_t base = (size_t)row * CC;
    x[base + tid]       = f2bf((v0 - mean) * rstd * w[tid]       + b[tid]);
    x[base + tid + 256] = f2bf((v1 - mean) * rstd * w[tid + 256] + b[tid + 256]);
    x[base + tid + 512] = f2bf((v2 - mean) * rstd * w[tid + 512] + b[tid + 512]);
}

// ---------------- GEMM: C[M,N] = A[M,K] @ Bt[N,K]^T  (bf16 in, f32 acc) ----------------
// Reg-staged (global->VGPR->LDS), single 32KB LDS buffer, 2-barrier loop,
// T14 async split; LDS XOR chunk-swizzle both-sides; XCD-chunked remap.
// EPI: 0 = bias -> bf16 out        (qkv)
//      1 = bias+gelu -> bf16 out   (fc)
//      2 = bias, residual add into f32 outf (proj, fc2)
//      3 = no bias, f32 logits out (col<VV) + per-block lse partials (lm_head)
template <int BM, int BN, int EPI>
__global__ __launch_bounds__(256)
void gemm_bt_kernel(const u16* __restrict__ A, const u16* __restrict__ Bt,
                    const float* __restrict__ bias, float* __restrict__ outf,
                    u16* __restrict__ outb, int K, long long ldo,
                    float* __restrict__ partM, float* __restrict__ partS) {
    constexpr int MR  = BM / 32, NR = BN / 32;   // fragment repeats per wave
    constexpr int ACH = BM * 64 / (256 * 8);     // staged A chunks per thread
    constexpr int BCH = BN * 64 / (256 * 8);
    __shared__ u16 As[BM * 64];
    __shared__ u16 Bs[BN * 64];
    const int tid  = threadIdx.x;
    const int lane = tid & 63;
    const int wid  = tid >> 6;
    const int l15  = lane & 15;
    const int lq   = lane >> 4;
    const int wm   = wid & 1;
    const int wn   = wid >> 1;
    const int rx   = l15 & 7;                    // read-side XOR chunk term

    // XCD-chunked bijective remap; work id is column-major (bx outer, by inner)
    const int gx = gridDim.x, gy = gridDim.y;
    const int nwg = gx * gy;
    const int pos = blockIdx.y * gx + blockIdx.x;      // dispatch order
    const int qc  = nwg >> 3, rc = nwg & 7;
    const int xcd = pos & 7, cidx = pos >> 3;
    const int wgid = (xcd < rc ? xcd * (qc + 1) : rc * (qc + 1) + (xcd - rc) * qc) + cidx;
    const int bx = wgid / gy, by = wgid % gy;
    const int bm0 = by * BM, bn0 = bx * BN;

    f32x4 acc[MR][NR];
#pragma unroll
    for (int m = 0; m < MR; ++m)
#pragma unroll
        for (int n = 0; n < NR; ++n) acc[m][n] = (f32x4){0.f, 0.f, 0.f, 0.f};

    u16x8 areg[ACH], breg[BCH];
    auto ldreg = [&](int kt) {
#pragma unroll
        for (int it = 0; it < ACH; ++it) {
            int g = it * 256 + tid, r = g >> 3, c = ((g & 7) ^ (r & 7)) * 8;
            areg[it] = *(const u16x8*)&A[(size_t)(bm0 + r) * (size_t)K + kt + c];
        }
#pragma unroll
        for (int it = 0; it < BCH; ++it) {
            int g = it * 256 + tid, r = g >> 3, c = ((g & 7) ^ (r & 7)) * 8;
            breg[it] = *(const u16x8*)&Bt[(size_t)(bn0 + r) * (size_t)K + kt + c];
        }
    };
    auto wlds = [&]() {
#pragma unroll
        for (int it = 0; it < ACH; ++it) *(u16x8*)&As[(it * 256 + tid) * 8] = areg[it];
#pragma unroll
        for (int it = 0; it < BCH; ++it) *(u16x8*)&Bs[(it * 256 + tid) * 8] = breg[it];
    };
    auto compute = [&]() {
#pragma unroll
        for (int ks = 0; ks < 2; ++ks) {
            s16x8 af[MR], bfr[NR];
#pragma unroll
            for (int m = 0; m < MR; ++m) {
                int row = wm * (BM / 2) + m * 16 + l15;
                af[m] = *(const s16x8*)&As[row * 64 + (((ks * 4 + lq) ^ rx) * 8)];
            }
#pragma unroll
            for (int n = 0; n < NR; ++n) {
                int row = wn * (BN / 2) + n * 16 + l15;
                bfr[n] = *(const s16x8*)&Bs[row * 64 + (((ks * 4 + lq) ^ rx) * 8)];
            }
#pragma unroll
            for (int m = 0; m < MR; ++m)
#pragma unroll
                for (int n = 0; n < NR; ++n)
                    acc[m][n] = __builtin_amdgcn_mfma_f32_16x16x32_bf16(af[m], bfr[n], acc[m][n], 0, 0, 0);
        }
    };

    const int nk = K >> 6;
    ldreg(0);
    for (int t = 0; t < nk; ++t) {
        __syncthreads();          // previous compute done; LDS free
        wlds();
        __syncthreads();          // tile visible to all waves
        if (t + 1 < nk) ldreg((t + 1) << 6);  // issue next loads under compute
        compute();
    }

    // epilogue: C/D layout col=lane&15, row=4*(lane>>4)+reg
#pragma unroll
    for (int m = 0; m < MR; ++m) {
#pragma unroll
        for (int n = 0; n < NR; ++n) {
#pragma unroll
            for (int r = 0; r < 4; ++r) {
                int row = bm0 + wm * (BM / 2) + m * 16 + lq * 4 + r;
                int col = bn0 + wn * (BN / 2) + n * 16 + l15;
                float v = acc[m][n][r];
                if (EPI != 3) v += bias[col];
                if (EPI == 1) {
                    float xg = v;
                    v = 0.5f * xg * (1.0f + tanhf(0.7978845608028654f * (xg + 0.044715f * xg * xg * xg)));
                }
                if (EPI == 0 || EPI == 1) {
                    outb[(size_t)row * ldo + col] = f2bf(v);
                } else if (EPI == 2) {
                    outf[(size_t)row * ldo + col] += v;
                } else {
                    if (col < VV) outf[(size_t)row * ldo + col] = v;
                }
            }
        }
    }

    // lm_head: per-row partial logsumexp over this block's BN cols
    if constexpr (EPI == 3) {
        __shared__ float redM[2][BM], redS[2][BM];
#pragma unroll
        for (int m = 0; m < MR; ++m) {
#pragma unroll
            for (int r = 0; r < 4; ++r) {
                float mx = -3.0e38f;
#pragma unroll
                for (int n = 0; n < NR; ++n) {
                    int colg = bn0 + wn * (BN / 2) + n * 16 + l15;
                    float v = (colg < VV) ? acc[m][n][r] : -3.0e38f;
                    mx = fmaxf(mx, v);
                }
#pragma unroll
                for (int off = 1; off < 16; off <<= 1) mx = fmaxf(mx, __shfl_xor(mx, off));
                float sm = 0.f;
#pragma unroll
                for (int n = 0; n < NR; ++n) {
                    int colg = bn0 + wn * (BN / 2) + n * 16 + l15;
                    if (colg < VV) sm += __expf(acc[m][n][r] - mx);
                }
#pragma unroll
                for (int off = 1; off < 16; off <<= 1) sm += __shfl_xor(sm, off);
                if (l15 == 0) {
                    int rl = wm * (BM / 2) + m * 16 + lq * 4 + r;
                    redM[wn][rl] = mx;
                    redS[wn][rl] = sm;
                }
            }
        }
        __syncthreads();
        if (tid < BM) {
            float m0 = redM[0][tid], m1 = redM[1][tid];
            float M = fmaxf(m0, m1);
            float S = redS[0][tid] * __expf(m0 - M) + redS[1][tid] * __expf(m1 - M);
            size_t rowg = (size_t)(bm0 + tid);
            partM[rowg * NBX + bx] = M;
            partS[rowg * NBX + bx] = S;
        }
    }
}

// ---------------- V transpose: qkv V-part [B][S][H*D] -> vT [B*H][D][S] ----------------
// 64x64 tile via chunk-XOR-swizzled LDS (vector writes, 2-way-free scalar reads).
__global__ __launch_bounds__(256) void vtrans_kernel(const u16* __restrict__ qkv,
                                                     u16* __restrict__ vT) {
    __shared__ u16 T[64 * 64];
    const int tid = threadIdx.x;
    const int t0  = blockIdx.x * 64;
    const int bh  = blockIdx.y;
    const int b   = bh / HH, hh = bh % HH;
    const u16* vp = qkv + (size_t)b * SS * (3 * CC) + 2 * CC + hh * DD;
#pragma unroll
    for (int it = 0; it < 2; ++it) {
        int g = it * 256 + tid;
        int t = g >> 3, dg = g & 7;
        u16x8 v = *(const u16x8*)&vp[(size_t)(t0 + t) * (3 * CC) + dg * 8];
        *(u16x8*)&T[(t * 8 + (dg ^ (t & 7))) * 8] = v;
    }
    __syncthreads();
    u16* op = vT + (size_t)bh * DD * SS + t0;
#pragma unroll
    for (int it = 0; it < 2; ++it) {
        int g = it * 256 + tid;
        int d = g >> 3, tc = g & 7;
        u16x8 o;
#pragma unroll
        for (int e = 0; e < 8; ++e) {
            int t = tc * 8 + e;
            o[e] = T[(t * 8 + ((d >> 3) ^ (t & 7))) * 8 + (d & 7)];
        }
        *(u16x8*)&op[(size_t)d * SS + tc * 8] = o;
    }
}

// ---------------- MFMA flash attention v2 (paired causal q-tiles) ----------------
// Block = (bh, jlo): q-tiles jlo and jhi=15-jlo; 4 waves x 16 rows each tile.
// One K/V staging loop over keys 0..jhi; lo-tile computes while t <= jlo.
// Uniform 17 tile-MFMA-units per block; grid = B*H*8 = 192.
__global__ __launch_bounds__(256) void attn_mfma2_kernel(const u16* __restrict__ qkv,
                                                         const u16* __restrict__ vT,
                                                         u16* __restrict__ o) {
    constexpr int PADC = 72;
    __shared__ u16 Ks[64][PADC];        // K[t][d]
    __shared__ u16 Vs[64][PADC];        // V^T[d][t]
    __shared__ u16 Ps[4][2][16][PADC];  // per-wave P tiles [hi/lo][row][t]

    const int tid = threadIdx.x, lane = tid & 63, wid = tid >> 6;
    const int l15 = lane & 15, lq = lane >> 4;
    // XCD mapping: the 8 pair-blocks of one bh land on one XCD
    const int pos = blockIdx.x;                       // 0..191
    const int bh  = (pos & 7) + 8 * ((pos >> 3) >> 3);
    const int jlo = (pos >> 3) & 7;
    const int jhi = 15 - jlo;
    const int b   = bh / HH, hh = bh % HH;
    const int q0lo = jlo * 64, q0hi = jhi * 64;

    const size_t base = (size_t)b * SS * (3 * CC);
    const u16* kp = qkv + base + CC + hh * DD;
    const u16* vp = vT + (size_t)bh * DD * SS;

    s16x8 qA[2], qB[2];
    {
        const u16* qr = qkv + base + hh * DD + (size_t)(q0hi + wid * 16 + l15) * (3 * CC);
        qA[0] = *(const s16x8*)&qr[lq * 8];
        qA[1] = *(const s16x8*)&qr[32 + lq * 8];
        const u16* qr2 = qkv + base + hh * DD + (size_t)(q0lo + wid * 16 + l15) * (3 * CC);
        qB[0] = *(const s16x8*)&qr2[lq * 8];
        qB[1] = *(const s16x8*)&qr2[32 + lq * 8];
    }

    float mA[4], lA[4], mB[4], lB[4];
    f32x4 oA[4], oB[4];
#pragma unroll
    for (int r = 0; r < 4; ++r) { mA[r] = mB[r] = -3.0e38f; lA[r] = lB[r] = 0.f; }
#pragma unroll
    for (int nd = 0; nd < 4; ++nd) { oA[nd] = (f32x4){0.f,0.f,0.f,0.f}; oB[nd] = (f32x4){0.f,0.f,0.f,0.f}; }

    // online softmax on a score tile; stores P to Ps[wid][ptile]
    auto smax = [&](f32x4 (&sc)[4], float (&m)[4], float (&lsum)[4], f32x4 (&acc)[4],
                    int ptile, int rowq0, bool diag, int t0) {
        if (diag) {
#pragma unroll
            for (int n = 0; n < 4; ++n) {
                int colg = t0 + n * 16 + l15;
#pragma unroll
                for (int r = 0; r < 4; ++r) {
                    int rowg = rowq0 + wid * 16 + lq * 4 + r;
                    float sv = sc[n][r] * 0.125f;
                    sc[n][r] = (colg <= rowg) ? sv : -3.0e38f;
                }
            }
        } else {
#pragma unroll
            for (int n = 0; n < 4; ++n)
#pragma unroll
                for (int r = 0; r < 4; ++r) sc[n][r] *= 0.125f;
        }
        float mt[4];
#pragma unroll
        for (int r = 0; r < 4; ++r)
            mt[r] = fmaxf(fmaxf(sc[0][r], sc[1][r]), fmaxf(sc[2][r], sc[3][r]));
#pragma unroll
        for (int off = 1; off < 16; off <<= 1)
#pragma unroll
            for (int r = 0; r < 4; ++r) mt[r] = fmaxf(mt[r], __shfl_xor(mt[r], off));
        float rs[4];
#pragma unroll
        for (int r = 0; r < 4; ++r) {
            float mn  = fmaxf(m[r], mt[r]);
            float scl = __expf(m[r] - mn);
            m[r] = mn;
            float ps = 0.f;
#pragma unroll
            for (int n = 0; n < 4; ++n) {
                float p = __expf(sc[n][r] - mn);
                sc[n][r] = p;
                ps += p;
            }
            rs[r] = ps;
            lsum[r] *= scl;
#pragma unroll
            for (int nd = 0; nd < 4; ++nd) acc[nd][r] *= scl;
        }
#pragma unroll
        for (int off = 1; off < 16; off <<= 1)
#pragma unroll
            for (int r = 0; r < 4; ++r) rs[r] += __shfl_xor(rs[r], off);
#pragma unroll
        for (int r = 0; r < 4; ++r) lsum[r] += rs[r];
#pragma unroll
        for (int n = 0; n < 4; ++n)
#pragma unroll
            for (int r = 0; r < 4; ++r)
                Ps[wid][ptile][lq * 4 + r][n * 16 + l15] = f2bf(sc[n][r]);
    };

    for (int tt = 0; tt <= jhi; ++tt) {
        const int t0 = tt * 64;
        const bool dolo = (tt <= jlo);
        __syncthreads();   // all waves done reading previous K/V tiles
#pragma unroll
        for (int it = 0; it < 2; ++it) {
            int g = it * 256 + tid;
            int r = g >> 3, c = (g & 7) * 8;
            *(u16x8*)&Ks[r][c] = *(const u16x8*)&kp[(size_t)(t0 + r) * (3 * CC) + c];
            *(u16x8*)&Vs[r][c] = *(const u16x8*)&vp[(size_t)r * SS + t0 + c];
        }
        __syncthreads();

        // QK^T both q-tiles, K fragments loaded once
        f32x4 sA[4], sB[4];
#pragma unroll
        for (int n = 0; n < 4; ++n) { sA[n] = (f32x4){0.f,0.f,0.f,0.f}; sB[n] = (f32x4){0.f,0.f,0.f,0.f}; }
#pragma unroll
        for (int ks = 0; ks < 2; ++ks) {
            s16x8 kb[4];
#pragma unroll
            for (int n = 0; n < 4; ++n)
                kb[n] = *(const s16x8*)&Ks[n * 16 + l15][ks * 32 + lq * 8];
#pragma unroll
            for (int n = 0; n < 4; ++n)
                sA[n] = __builtin_amdgcn_mfma_f32_16x16x32_bf16(qA[ks], kb[n], sA[n], 0, 0, 0);
            if (dolo) {
#pragma unroll
                for (int n = 0; n < 4; ++n)
                    sB[n] = __builtin_amdgcn_mfma_f32_16x16x32_bf16(qB[ks], kb[n], sB[n], 0, 0, 0);
            }
        }

        smax(sA, mA, lA, oA, 0, q0hi, tt == jhi, t0);
        if (dolo) smax(sB, mB, lB, oB, 1, q0lo, tt == jlo, t0);

        // PV: V fragments loaded once, feed both P tiles (Ps is wave-private; no barrier)
#pragma unroll
        for (int ks = 0; ks < 2; ++ks) {
            s16x8 vb[4];
#pragma unroll
            for (int nd = 0; nd < 4; ++nd)
                vb[nd] = *(const s16x8*)&Vs[nd * 16 + l15][ks * 32 + lq * 8];
            s16x8 paA = *(const s16x8*)&Ps[wid][0][l15][ks * 32 + lq * 8];
#pragma unroll
            for (int nd = 0; nd < 4; ++nd)
                oA[nd] = __builtin_amdgcn_mfma_f32_16x16x32_bf16(paA, vb[nd], oA[nd], 0, 0, 0);
            if (dolo) {
                s16x8 paB = *(const s16x8*)&Ps[wid][1][l15][ks * 32 + lq * 8];
#pragma unroll
                for (int nd = 0; nd < 4; ++nd)
                    oB[nd] = __builtin_amdgcn_mfma_f32_16x16x32_bf16(paB, vb[nd], oB[nd], 0, 0, 0);
            }
        }
    }

    auto writeO = [&](float (&lsum)[4], f32x4 (&acc)[4], int rowq0) {
#pragma unroll
        for (int r = 0; r < 4; ++r) {
            float inv = 1.f / lsum[r];
            int rowg = rowq0 + wid * 16 + lq * 4 + r;
            u16* orow = o + ((size_t)b * SS + rowg) * CC + hh * DD;
#pragma unroll
            for (int nd = 0; nd < 4; ++nd)
                orow[nd * 16 + l15] = f2bf(acc[nd][r] * inv);
        }
    };
    writeO(lA, oA, q0hi);
    writeO(lB, oB, q0lo);
}

// ---------------- loss (from lm_head partials) ----------------
__global__ __launch_bounds__(256) void lse_kernel(const float* __restrict__ partM,
                                                  const float* __restrict__ partS,
                                                  const float* __restrict__ logits,
                                                  const int* __restrict__ tgt,
                                                  float* __restrict__ lossp) {
    int row = blockIdx.x, tid = threadIdx.x;
    float m = -3.0e38f, s = 0.f;
    for (int i = tid; i < NBX; i += 256) {
        float pm = partM[(size_t)row * NBX + i];
        float ps = partS[(size_t)row * NBX + i];
        float nm = fmaxf(m, pm);
        s = s * __expf(m - nm) + ps * __expf(pm - nm);
        m = nm;
    }
#pragma unroll
    for (int off = 32; off; off >>= 1) {
        float om = __shfl_xor(m, off), os = __shfl_xor(s, off);
        float nm = fmaxf(m, om);
        s = s * __expf(m - nm) + os * __expf(om - nm);
        m = nm;
    }
    __shared__ float rm[4], rsh[4];
    int wid = tid >> 6;
    if ((tid & 63) == 0) { rm[wid] = m; rsh[wid] = s; }
    __syncthreads();
    if (tid == 0) {
        float M = fmaxf(fmaxf(rm[0], rm[1]), fmaxf(rm[2], rm[3]));
        float S = rsh[0] * __expf(rm[0] - M) + rsh[1] * __expf(rm[1] - M) +
                  rsh[2] * __expf(rm[2] - M) + rsh[3] * __expf(rm[3] - M);
        float lse = M + __logf(S);
        lossp[row] = lse - logits[(size_t)row * VV + tgt[row]];
    }
}

__global__ __launch_bounds__(256) void loss_reduce_kernel(const float* __restrict__ lossp,
                                                          float* __restrict__ out) {
    int tid = threadIdx.x;
    float s = 0.f;
    for (int i = tid; i < MM; i += 256) s += lossp[i];
#pragma unroll
    for (int off = 32; off; off >>= 1) s += __shfl_xor(s, off);
    __shared__ float r[4];
    if ((tid & 63) == 0) r[tid >> 6] = s;
    __syncthreads();
    if (tid == 0) out[0] = (r[0] + r[1] + r[2] + r[3]) * (1.0f / MM);
}

// ---------------- host ----------------
extern "C" void kernel_launch(void* const* d_in, const int* in_sizes, int n_in,
                              void* d_out, int out_size, void* d_ws, size_t ws_size,
                              hipStream_t stream) {
    const int*   idx     = (const int*)  d_in[0];
    const int*   targets = (const int*)  d_in[1];
    const float* wte     = (const float*)d_in[2];
    const float* wpe     = (const float*)d_in[3];
    const float* ln1w    = (const float*)d_in[4];
    const float* ln1b    = (const float*)d_in[5];
    const float* qkvw    = (const float*)d_in[6];
    const float* qkvbi   = (const float*)d_in[7];
    const float* projw   = (const float*)d_in[8];
    const float* projbi  = (const float*)d_in[9];
    const float* ln2w    = (const float*)d_in[10];
    const float* ln2b    = (const float*)d_in[11];
    const float* fcw     = (const float*)d_in[12];
    const float* fcbi    = (const float*)d_in[13];
    const float* fc2w    = (const float*)d_in[14];
    const float* fc2bi   = (const float*)d_in[15];
    const float* lnfw    = (const float*)d_in[16];
    const float* lnfb    = (const float*)d_in[17];
    float* logits = (float*)d_out;

    char* wsb = (char*)d_ws;
    size_t off = 0;
    auto alloc = [&](size_t n) -> char* {
        char* p = wsb + off;
        off = (off + n + 255) & ~(size_t)255;
        return p;
    };
    u16*   wteT  = (u16*)  alloc((size_t)VPAD * CC * 2);
    u16*   qkvT  = (u16*)  alloc((size_t)LNUM * 3 * CC * CC * 2);
    u16*   projT = (u16*)  alloc((size_t)LNUM * CC * CC * 2);
    u16*   fcT   = (u16*)  alloc((size_t)LNUM * FFD * CC * 2);
    u16*   fc2T  = (u16*)  alloc((size_t)LNUM * CC * FFD * 2);
    float* h     = (float*)alloc((size_t)MM * CC * 4);
    u16*   xb    = (u16*)  alloc((size_t)MM * CC * 2);
    u16*   qkvb  = (u16*)  alloc((size_t)MM * 3 * CC * 2);
    u16*   ob    = (u16*)  alloc((size_t)MM * CC * 2);
    u16*   gb    = (u16*)  alloc((size_t)MM * FFD * 2);
    u16*   vTb   = (u16*)  alloc((size_t)BB * HH * DD * SS * 2);
    float* lossp = (float*)alloc((size_t)MM * 4);
    float* partM = (float*)alloc((size_t)MM * NBX * 4);
    float* partS = (float*)alloc((size_t)MM * NBX * 4);

    // weight prep
    {
        int blocks = (int)(((size_t)VPAD * CC / 4 + 255) / 256);
        wte_conv_kernel<<<blocks, 256, 0, stream>>>(wte, wteT);
    }
    transpose_conv_kernel<<<dim3(3 * CC / 32, CC / 32, LNUM), dim3(32, 8), 0, stream>>>(qkvw, qkvT, CC, 3 * CC);
    transpose_conv_kernel<<<dim3(CC / 32, CC / 32, LNUM),     dim3(32, 8), 0, stream>>>(projw, projT, CC, CC);
    transpose_conv_kernel<<<dim3(FFD / 32, CC / 32, LNUM),    dim3(32, 8), 0, stream>>>(fcw, fcT, CC, FFD);
    transpose_conv_kernel<<<dim3(CC / 32, FFD / 32, LNUM),    dim3(32, 8), 0, stream>>>(fc2w, fc2T, FFD, CC);

    embed_kernel<<<MM, 256, 0, stream>>>(idx, wte, wpe, h);

    for (int l = 0; l < LNUM; ++l) {
        const u16* qkvT_l  = qkvT  + (size_t)l * 3 * CC * CC;
        const u16* projT_l = projT + (size_t)l * CC * CC;
        const u16* fcT_l   = fcT   + (size_t)l * FFD * CC;
        const u16* fc2T_l  = fc2T  + (size_t)l * CC * FFD;

        ln_kernel<<<MM, 256, 0, stream>>>(h, ln1w + (size_t)l * CC, ln1b + (size_t)l * CC, xb);
        gemm_bt_kernel<128, 128, 0><<<dim3(3 * CC / 128, MM / 128), 256, 0, stream>>>(
            xb, qkvT_l, qkvbi + (size_t)l * 3 * CC, nullptr, qkvb, CC, 3 * CC, nullptr, nullptr);
        vtrans_kernel<<<dim3(SS / 64, BB * HH), 256, 0, stream>>>(qkvb, vTb);
        attn_mfma2_kernel<<<BB * HH * 8, 256, 0, stream>>>(qkvb, vTb, ob);
        gemm_bt_kernel<64, 64, 2><<<dim3(CC / 64, MM / 64), 256, 0, stream>>>(
            ob, projT_l, projbi + (size_t)l * CC, h, nullptr, CC, CC, nullptr, nullptr);
        ln_kernel<<<MM, 256, 0, stream>>>(h, ln2w + (size_t)l * CC, ln2b + (size_t)l * CC, xb);
        gemm_bt_kernel<128, 128, 1><<<dim3(FFD / 128, MM / 128), 256, 0, stream>>>(
            xb, fcT_l, fcbi + (size_t)l * FFD, nullptr, gb, CC, FFD, nullptr, nullptr);
        gemm_bt_kernel<64, 64, 2><<<dim3(CC / 64, MM / 64), 256, 0, stream>>>(
            gb, fc2T_l, fc2bi + (size_t)l * CC, h, nullptr, FFD, CC, nullptr, nullptr);
    }

    ln_kernel<<<MM, 256, 0, stream>>>(h, lnfw, lnfb, xb);
    gemm_bt_kernel<128, 128, 3><<<dim3(VPAD / 128, MM / 128), 256, 0, stream>>>(
        xb, wteT, nullptr, logits, nullptr, CC, VV, partM, partS);

    lse_kernel<<<MM, 256, 0, stream>>>(partM, partS, logits, targets, lossp);
    loss_reduce_kernel<<<1, 256, 0, stream>>>(lossp, logits + (size_t)MM * VV);
}